// Round 3
// baseline (379.684 us; speedup 1.0000x reference)
//
#include <hip/hip_runtime.h>

// CrossSymmetricModal: two cross-attention branches. B=16, C=256, L=1024.
// Convs are NT-GEMMs over padded transposed activations with tap-major K.
// R9: flash attention (S never hits HBM). R10: XCD-swizzled grids, bf16 Y +
// BN stats fused into o-conv epilogue.
// R13: flash_attn restructured around swapped-operand 32x32x16 MFMAs:
//   S = mfma(K,Q) -> each lane holds P for ONE Q-row (col=lane&31), so the
//   softmax denominator is a per-lane scalar (one shfl_xor(32) total) and P
//   is converted to PV B-fragments IN REGISTERS via v_cvt_pk_bf16_f32 +
//   v_permlane32_swap_b32 (word0=[A.lo|C.lo], w1=[B.lo|D.lo], w2=[A.hi|C.hi],
//   w3=[B.hi|D.hi]).  ZERO barriers in the main loop; LDS only for the
//   epilogue transpose.  Wave = (row-group x channel-half); QK duplicated
//   per pair (MFMA x1.5) to stay barrier-free.
// Output [16][512][1024] fp32.

typedef short bf16x8 __attribute__((ext_vector_type(8)));
typedef float f32x4 __attribute__((ext_vector_type(4)));
typedef float f32x16 __attribute__((ext_vector_type(16)));

__device__ __forceinline__ unsigned short f2bf(float f) {
    union { float f; unsigned u; } v; v.f = f;
    unsigned r = v.u + 0x7fffu + ((v.u >> 16) & 1u);   // RNE
    return (unsigned short)(r >> 16);
}
__device__ __forceinline__ float bf2f(unsigned short h) {
    union { unsigned u; float f; } v; v.u = ((unsigned)h) << 16;
    return v.f;
}

// pack two f32 -> two bf16 (RNE), low word from lo
__device__ __forceinline__ unsigned cvt_pk_bf16(float lo, float hi) {
    unsigned r;
    asm("v_cvt_pk_bf16_f32 %0, %1, %2" : "=v"(r) : "v"(lo), "v"(hi));
    return r;
}
// v_permlane32_swap_b32: a' = [a.lo | b.lo], b' = [a.hi | b.hi]
__device__ __forceinline__ void plane32_swap(unsigned& a, unsigned& b) {
    asm volatile("v_permlane32_swap_b32 %0, %1" : "+v"(a), "+v"(b));
}

// async global->LDS, 16B per lane; HW writes lane i at lds_base + i*16 (m97/m104)
__device__ __forceinline__ void glds16(const void* g, void* l) {
    __builtin_amdgcn_global_load_lds(
        (const __attribute__((address_space(1))) unsigned int*)g,
        (__attribute__((address_space(3))) unsigned int*)l, 16, 0, 0);
}

// ---------------------------------------------------------------------------
// NT GEMM: 2-op batched, compact 1-D grid, double-buffered glds staging,
// LDS-transpose epilogue with coalesced 16B stores.
// ---------------------------------------------------------------------------
#define TM 128
#define TN 128
#define BK 32

struct GOp {
    const unsigned short* A; const unsigned short* B; void* C;
    long sA, sB, sC;
    int lda, ldb, ldc, nxt, nyt, nz;
    const float* bias_row; const float* bias_col;
    float* stats; int stat_base;      // stats!=null: atomicAdd sum/sumsq per row
};

__global__ __launch_bounds__(256)
void gemm_nt(GOp op0, GOp op1, int n0, int K, float alpha)
{
    __shared__ __attribute__((aligned(16))) char sh[34816];
    unsigned short* shs = (unsigned short*)sh;
    int id = blockIdx.x;
    const bool brn = (id >= n0);
    const GOp op = brn ? op1 : op0;
    if (brn) id -= n0;
    const int bz = id % op.nz;          // XCD swizzle
    const int rem = id / op.nz;
    const int by = rem / op.nxt;
    const int bx = rem - by * op.nxt;

    const unsigned short* Ab = op.A + op.sA * bz;
    const unsigned short* Bb = op.B + op.sB * bz;
    const int lda = op.lda, ldb = op.ldb;
    const int i0 = by * TM;
    const int j0 = bx * TN;
    const int t = threadIdx.x;
    const int lane = t & 63;
    const int wave = t >> 6;
    const int wm = wave & 1, wn = wave >> 1;

    const int srow = wave * 16 + (lane >> 2);
    const int sc8 = (lane & 3) * 8;
    const unsigned short* gA0 = Ab + (long)(i0 + srow) * lda + sc8;
    const unsigned short* gA1 = gA0 + (long)64 * lda;
    const unsigned short* gB0 = Bb + (long)(j0 + srow) * ldb + sc8;
    const unsigned short* gB1 = gB0 + (long)64 * ldb;
    const int d0 = wave * 512;
    const int d1 = 2048 + wave * 512;

    f32x4 acc[4][4];
#pragma unroll
    for (int a_ = 0; a_ < 4; ++a_)
#pragma unroll
        for (int b_ = 0; b_ < 4; ++b_)
            acc[a_][b_] = (f32x4){0.f, 0.f, 0.f, 0.f};

    const int frow = lane & 15;
    const int fk = (lane >> 4) * 8;

    glds16(gA0, shs + d0);
    glds16(gA1, shs + d1);
    glds16(gB0, shs + 8192 + d0);
    glds16(gB1, shs + 8192 + d1);

    int cur = 0;
    for (int k0 = 0; k0 < K; k0 += BK) {
        __syncthreads();
        const int kn = k0 + BK;
        if (kn < K) {
            const int nb = cur ^ 1;
            glds16(gA0 + kn, shs + nb * 4096 + d0);
            glds16(gA1 + kn, shs + nb * 4096 + d1);
            glds16(gB0 + kn, shs + 8192 + nb * 4096 + d0);
            glds16(gB1 + kn, shs + 8192 + nb * 4096 + d1);
        }
        const unsigned short* la = shs + cur * 4096;
        const unsigned short* lb = shs + 8192 + cur * 4096;
        bf16x8 af[4], bfr[4];
#pragma unroll
        for (int mt = 0; mt < 4; ++mt)
            af[mt] = *(const bf16x8*)(&la[(wm * 64 + mt * 16 + frow) * BK + fk]);
#pragma unroll
        for (int nt = 0; nt < 4; ++nt)
            bfr[nt] = *(const bf16x8*)(&lb[(wn * 64 + nt * 16 + frow) * BK + fk]);
#pragma unroll
        for (int mt = 0; mt < 4; ++mt)
#pragma unroll
            for (int nt = 0; nt < 4; ++nt)
                acc[mt][nt] = __builtin_amdgcn_mfma_f32_16x16x32_bf16(af[mt], bfr[nt], acc[mt][nt], 0, 0, 0);
        cur ^= 1;
    }

    const int lr = (lane >> 4) * 4;   // C/D: row=(lane>>4)*4+reg, col=lane&15 (m89/m91)
    const int lc = lane & 15;
    __syncthreads();

    unsigned short* tile = shs;       // [128][136]
#pragma unroll
    for (int mt = 0; mt < 4; ++mt) {
#pragma unroll
        for (int nt = 0; nt < 4; ++nt) {
            const int col = wn * 64 + nt * 16 + lc;
            const float bc = op.bias_col ? op.bias_col[j0 + col] : 0.f;
#pragma unroll
            for (int r = 0; r < 4; ++r) {
                const int row = wm * 64 + mt * 16 + lr + r;
                const float brv = op.bias_row ? op.bias_row[i0 + row] : 0.f;
                tile[row * 136 + col] = f2bf(acc[mt][nt][r] * alpha + brv + bc);
            }
        }
    }
    __syncthreads();
    unsigned short* Cb = (unsigned short*)op.C + op.sC * bz;
#pragma unroll
    for (int p = 0; p < 8; ++p) {
        const int cid = p * 256 + t;
        const int row = cid >> 4;
        const int c8 = (cid & 15) * 8;
        const uint4 v = *(const uint4*)(tile + row * 136 + c8);
        *(uint4*)(Cb + (long)(i0 + row) * op.ldc + j0 + c8) = v;
    }
    if (op.stats) {
        // per-channel (row) partial sums of the bf16 tile; 2 threads/row
        const int row = t >> 1, half = t & 1;
        float s = 0.f, s2 = 0.f;
#pragma unroll
        for (int c = 0; c < 64; c += 8) {
            const bf16x8 v = *(const bf16x8*)(tile + row * 136 + half * 64 + c);
#pragma unroll
            for (int e = 0; e < 8; ++e) {
                const float f = bf2f((unsigned short)v[e]);
                s += f; s2 += f * f;
            }
        }
        s += __shfl_xor(s, 1);
        s2 += __shfl_xor(s2, 1);
        if (half == 0) {
            const int ch = op.stat_base + i0 + row;
            atomicAdd(&op.stats[ch], s);
            atomicAdd(&op.stats[512 + ch], s2);
        }
    }
}

// ---------------------------------------------------------------------------
// R13 flash attention.  256 threads / 4 waves; 64 Q-rows per block.
// wave w: rg = w&1 (rows rg*32..+32), ch = w>>1 (PV channels ch*128..+128).
// Swapped QK^T: S = mfma_32x32x16(A=K[key][c], B=Q[c][qrow]) -> lane holds
// P[key][qrow=lane&31]; per-lane denominator; P->B-frag via cvt_pk+permlane.
// No LDS / no barriers in main loop.  No max-subtraction (S/16 sigma~1.9 =>
// exp<=4e4, f32-safe; softmax shift-invariant).
// ---------------------------------------------------------------------------
__global__ __launch_bounds__(256, 2)
void flash_attn(const unsigned short* __restrict__ QK,
                const unsigned short* __restrict__ qTb,
                const unsigned short* __restrict__ kTa,
                const unsigned short* __restrict__ va,
                const unsigned short* __restrict__ vb,
                unsigned short* __restrict__ ctxT)
{
    __shared__ __attribute__((aligned(16))) unsigned short Qs[64 * 264];  // epilogue only

    const long sQK = 1024L * 512, sQT = 1024L * 256, sV = 256L * 1024;
    const int bid = blockIdx.x;            // 512 = 16 strips x 32 z (z fastest!)
    const int z = bid & 31;
    const int l0 = (bid >> 5) * 64;
    const bool bb = (z >= 16);
    const int zz = bb ? z - 16 : z;
    const unsigned short* Qg = bb ? (qTb + (long)zz * sQT) : (QK + (long)zz * sQK);
    const int ldq = bb ? 256 : 512;
    const unsigned short* Kg = bb ? (QK + (long)zz * sQK + 256) : (kTa + (long)zz * sQT);
    const int ldk = bb ? 512 : 256;
    const unsigned short* Vg = (bb ? vb : va) + (long)zz * sV;       // [c][m] ld 1024
    unsigned short* Og = ctxT + ((long)z * 1026 + 1 + l0) * 256;     // [64][256]

    const int t = threadIdx.x;
    const int lane = t & 63, w = t >> 6;
    const int rg = w & 1, ch = w >> 1;
    const int lr = lane & 31, h = lane >> 5;

    // Q B-fragments: col=qrow=lr, k = kc*16 + 8h + e  (loaded once, 64 VGPR)
    const unsigned short* Qrow = Qg + (long)(l0 + rg * 32 + lr) * ldq + h * 8;
    bf16x8 qf[16];
#pragma unroll
    for (int kc = 0; kc < 16; ++kc)
        qf[kc] = *(const bf16x8*)(Qrow + kc * 16);

    f32x16 acc_o[4];
#pragma unroll
    for (int ct = 0; ct < 4; ++ct)
        acc_o[ct] = (f32x16){0.f,0.f,0.f,0.f,0.f,0.f,0.f,0.f,
                             0.f,0.f,0.f,0.f,0.f,0.f,0.f,0.f};
    float dsum = 0.f;

    const unsigned short* Krow = Kg + (long)lr * ldk + h * 8;
    const unsigned short* Vrow = Vg + (long)(ch * 128 + lr) * 1024 + h * 8;

    for (int m0 = 0; m0 < 1024; m0 += 32) {
        // --- K A-fragments for this 32-key chunk: row=key=lr, k per chunk ---
        const unsigned short* Kp = Krow + (long)m0 * ldk;
        bf16x8 kf[16];
#pragma unroll
        for (int kc = 0; kc < 16; ++kc)
            kf[kc] = *(const bf16x8*)(Kp + kc * 16);
        // --- QK^T (swapped): S[key][qrow] ---
        f32x16 s = (f32x16){0.f,0.f,0.f,0.f,0.f,0.f,0.f,0.f,
                            0.f,0.f,0.f,0.f,0.f,0.f,0.f,0.f};
#pragma unroll
        for (int kc = 0; kc < 16; ++kc)
            s = __builtin_amdgcn_mfma_f32_32x32x16_bf16(kf[kc], qf[kc], s, 0, 0, 0);
        // --- exp + per-lane denominator (key = (reg&3)+8*(reg>>2)+4h) ---
        float p[16];
#pragma unroll
        for (int r = 0; r < 16; ++r) {
            p[r] = __expf(s[r] * 0.0625f);
            dsum += p[r];
        }
        // --- P -> PV B-fragments in registers + PV MFMAs ---
#pragma unroll
        for (int u = 0; u < 2; ++u) {
            unsigned A = cvt_pk_bf16(p[u*8+0], p[u*8+1]);
            unsigned B = cvt_pk_bf16(p[u*8+2], p[u*8+3]);
            unsigned C = cvt_pk_bf16(p[u*8+4], p[u*8+5]);
            unsigned D = cvt_pk_bf16(p[u*8+6], p[u*8+7]);
            plane32_swap(A, C);   // A=word0=[A.lo|C.lo], C=word2=[A.hi|C.hi]
            plane32_swap(B, D);   // B=word1, D=word3
            union { unsigned u4[4]; bf16x8 v; } pf;
            pf.u4[0] = A; pf.u4[1] = B; pf.u4[2] = C; pf.u4[3] = D;
            const unsigned short* Vp = Vrow + m0 + u * 16;
#pragma unroll
            for (int ct = 0; ct < 4; ++ct) {
                const bf16x8 vf = *(const bf16x8*)(Vp + (long)ct * 32 * 1024);
                acc_o[ct] = __builtin_amdgcn_mfma_f32_32x32x16_bf16(vf, pf.v, acc_o[ct], 0, 0, 0);
            }
        }
    }

    // --- denominator: other key-half lives in lane^32 ---
    dsum += __shfl_xor(dsum, 32);
    const float inv = 1.f / dsum;

    // --- epilogue: normalize, LDS transpose, coalesced 16B stores ---
    // lane's O: qrow = rg*32+lr; c = ch*128 + ct*32 + gr*8 + 4h + {0..3}
    unsigned short* Qw = Qs + (rg * 32 + lr) * 264 + ch * 128 + h * 4;
#pragma unroll
    for (int ct = 0; ct < 4; ++ct)
#pragma unroll
        for (int gr = 0; gr < 4; ++gr) {
            const int r0 = gr * 4;
            uint2 wv;
            wv.x = cvt_pk_bf16(acc_o[ct][r0]     * inv, acc_o[ct][r0 + 1] * inv);
            wv.y = cvt_pk_bf16(acc_o[ct][r0 + 2] * inv, acc_o[ct][r0 + 3] * inv);
            *(uint2*)(Qw + ct * 32 + gr * 8) = wv;
        }
    __syncthreads();
#pragma unroll
    for (int p8 = 0; p8 < 8; ++p8) {
        const int cid = p8 * 256 + t, row = cid >> 5, c8 = (cid & 31) * 8;
        *(uint4*)(Og + (long)row * 256 + c8) = *(const uint4*)(Qs + row * 264 + c8);
    }
}

// ---------------------------------------------------------------------------
// Fused prep; tail now also zeroes the BN stats accumulators (grid 5478).
// ---------------------------------------------------------------------------
__global__ __launch_bounds__(256)
void prep(const float* __restrict__ image, const float* __restrict__ cli,
          const float* __restrict__ a_qw, const float* __restrict__ a_qb,
          const float* __restrict__ a_kw, const float* __restrict__ a_kb,
          const float* __restrict__ a_vw, const float* __restrict__ a_vb,
          const float* __restrict__ a_ow,
          const float* __restrict__ b_qw, const float* __restrict__ b_qb,
          const float* __restrict__ b_kw, const float* __restrict__ b_kb,
          const float* __restrict__ b_vw, const float* __restrict__ b_vb,
          const float* __restrict__ b_ow,
          unsigned short* __restrict__ imgT, unsigned short* __restrict__ ctxT,
          unsigned short* __restrict__ kTa, unsigned short* __restrict__ va,
          unsigned short* __restrict__ qTb,
          unsigned short* __restrict__ W, float* __restrict__ qkb,
          float* __restrict__ sums)
{
    __shared__ char smem[64 * 65 * 4];
    const int b = blockIdx.x;
    const int t = threadIdx.x;
    if (b < 1024) {
        float* tile = (float*)smem;                      // [64][65]
        const int bt = b >> 6, rem = b & 63;
        const int l0 = (rem & 15) * 64, c0 = (rem >> 4) * 64;
        const float* xb = image + ((long)bt * 256 + c0) * 1024 + l0;
        for (int idx = t; idx < 4096; idx += 256) {
            const int cc = idx >> 6, ll = idx & 63;
            tile[cc * 65 + ll] = xb[(long)cc * 1024 + ll];
        }
        __syncthreads();
        unsigned short* op = imgT + ((long)bt * 1026 + l0 + 1) * 256 + c0;
        for (int idx = t; idx < 4096; idx += 256) {
            const int ll = idx >> 6, cc = idx & 63;
            op[(long)ll * 256 + cc] = f2bf(tile[cc * 65 + ll]);
        }
    } else if (b < 1536) {
        float* xs = (float*)smem;                        // [34]
        const int local = b - 1024;
        const int bz = local >> 5;
        const int l0 = (local & 31) * 32;
        if (t < 34) {
            const int l = l0 + t - 1;
            xs[t] = (l >= 0 && l < 1024) ? cli[(long)bz * 1024 + l] : 0.f;
        }
        __syncthreads();
        for (int i = t; i < 32 * 256; i += 256) {        // [l][c] outputs
            const int r = i >> 8, c = i & 255;
            const float x0 = xs[r], x1 = xs[r + 1], x2 = xs[r + 2];
            const float kv = a_kw[c * 3] * x0 + a_kw[c * 3 + 1] * x1 + a_kw[c * 3 + 2] * x2 + a_kb[c];
            const float qv = b_qw[c * 3] * x0 + b_qw[c * 3 + 1] * x1 + b_qw[c * 3 + 2] * x2 + b_qb[c];
            const long base = ((long)bz * 1024 + l0 + r) * 256 + c;
            kTa[base] = f2bf(kv);
            qTb[base] = f2bf(qv);
        }
        for (int i = t; i < 32 * 256; i += 256) {        // [c][l] output
            const int c = i >> 5, r = i & 31;
            const float x0 = xs[r], x1 = xs[r + 1], x2 = xs[r + 2];
            const float vv = a_vw[c * 3] * x0 + a_vw[c * 3 + 1] * x1 + a_vw[c * 3 + 2] * x2 + a_vb[c];
            va[((long)bz * 256 + c) * 1024 + l0 + r] = f2bf(vv);
        }
    } else if (b < 5376) {
        const int i = (b - 1536) * 256 + t;              // 0..983039
        const int row = i / 768;
        const int kk = i - row * 768;
        const int j = kk >> 8, ci = kk & 255;
        const float* src = (row < 256) ? a_qw : (row < 512) ? b_kw
                         : (row < 768) ? b_vw : (row < 1024) ? a_ow : b_ow;
        const int r = row & 255;
        W[i] = f2bf(src[r * 768 + ci * 3 + j]);
    } else {
        const int i = (b - 5376) * 256 + t;              // 0..26111
        if (i < 512) {
            qkb[i] = (i < 256) ? a_qb[i] : b_kb[i - 256];
        } else if (i < 512 + 8192) {
            const int p = i - 512;                       // imgT pad rows
            const int bi = p >> 9, rr = (p >> 8) & 1, c = p & 255;
            imgT[((long)bi * 1026 + (rr ? 1025 : 0)) * 256 + c] = 0;
        } else if (i < 512 + 8192 + 16384) {
            const int p = i - 512 - 8192;                // ctxT pad rows
            const int bz = p >> 9, rr = (p >> 8) & 1, c = p & 255;
            ctxT[((long)bz * 1026 + (rr ? 1025 : 0)) * 256 + c] = 0;
        } else if (i < 512 + 8192 + 16384 + 1024) {
            sums[i - 512 - 8192 - 16384] = 0.f;          // BN accumulators
        }
    }
}

// ---------------------------------------------------------------------------
// BN finalize: sums[ch], sums[512+ch] -> ss scale/shift.  2 blocks.
// ---------------------------------------------------------------------------
__global__ __launch_bounds__(256)
void bn_finalize(const float* __restrict__ sums,
                 const float* __restrict__ ag, const float* __restrict__ abeta,
                 const float* __restrict__ bg, const float* __restrict__ bbeta,
                 float* __restrict__ ss)
{
    const int ch = blockIdx.x * 256 + threadIdx.x;
    const int branch = ch >> 8, c = ch & 255;
    const float mean = sums[ch] * (1.f / 16384.f);
    const float var = sums[512 + ch] * (1.f / 16384.f) - mean * mean;  // biased
    const float inv = rsqrtf(var + 1e-5f);
    const float g = branch ? bg[c] : ag[c];
    const float be = branch ? bbeta[c] : abeta[c];
    const float sc = g * inv;
    ss[ch] = sc;
    ss[512 + ch] = be - mean * sc;
}

// out[b][ch][l] = y*scale + shift + image[b][ch&255][l]  (Y is bf16 now)
__global__ __launch_bounds__(256)
void bn_apply(const unsigned short* __restrict__ Y, const float* __restrict__ img,
              const float* __restrict__ ss, float* __restrict__ out)
{
    const long i4 = (long)blockIdx.x * 256 + threadIdx.x;
    const long e = i4 * 4;
    const int l = (int)(e & 1023);
    const int ch = (int)((e >> 10) & 511);
    const int b = (int)(e >> 19);
    const int branch = ch >> 8, c = ch & 255;
    const float sc = ss[ch], sh = ss[512 + ch];
    const long yoff = (((long)(branch * 16 + b)) * 256 + c) * 1024 + l;
    const long ioff = ((long)b * 256 + c) * 1024 + l;
    const ushort4 yv = *(const ushort4*)(Y + yoff);
    const float4 iv = *(const float4*)(img + ioff);
    float4 o;
    o.x = bf2f(yv.x) * sc + sh + iv.x;
    o.y = bf2f(yv.y) * sc + sh + iv.y;
    o.z = bf2f(yv.z) * sc + sh + iv.z;
    o.w = bf2f(yv.w) * sc + sh + iv.w;
    *(float4*)(out + e) = o;
}

// ---------------------------------------------------------------------------
extern "C" void kernel_launch(void* const* d_in, const int* in_sizes, int n_in,
                              void* d_out, int out_size, void* d_ws, size_t ws_size,
                              hipStream_t stream)
{
    const float* image    = (const float*)d_in[0];
    const float* clinical = (const float*)d_in[1];
    const float* a_qw = (const float*)d_in[2];  const float* a_qb = (const float*)d_in[3];
    const float* a_kw = (const float*)d_in[4];  const float* a_kb = (const float*)d_in[5];
    const float* a_vw = (const float*)d_in[6];  const float* a_vb = (const float*)d_in[7];
    const float* a_ow = (const float*)d_in[8];  const float* a_ob = (const float*)d_in[9];
    const float* a_g  = (const float*)d_in[10]; const float* a_be = (const float*)d_in[11];
    const float* b_qw = (const float*)d_in[12]; const float* b_qb = (const float*)d_in[13];
    const float* b_kw = (const float*)d_in[14]; const float* b_kb = (const float*)d_in[15];
    const float* b_vw = (const float*)d_in[16]; const float* b_vb = (const float*)d_in[17];
    const float* b_ow = (const float*)d_in[18]; const float* b_ob = (const float*)d_in[19];
    const float* b_g  = (const float*)d_in[20]; const float* b_be = (const float*)d_in[21];
    float* out = (float*)d_out;

    char* ws = (char*)d_ws;
    const long MB = 1048576L;
    unsigned short* imgT = (unsigned short*)(ws);              // [16][1026][256] bf16
    unsigned short* ctxT = (unsigned short*)(ws + 9 * MB);     // [32][1026][256] bf16
    unsigned short* kTa  = (unsigned short*)(ws + 27 * MB);    // [16][1024][256]
    unsigned short* qTb  = (unsigned short*)(ws + 36 * MB);
    unsigned short* va   = (unsigned short*)(ws + 46 * MB);    // [16][256][1024]
    unsigned short* vb   = (unsigned short*)(ws + 54 * MB);
    unsigned short* QK   = (unsigned short*)(ws + 62 * MB);    // [16][1024][512]
    unsigned short* Y    = (unsigned short*)(ws + 142 * MB);   // [32][256][1024] bf16
    unsigned short* W    = (unsigned short*)(ws + 174 * MB);   // [1280][768] bf16 tap-major
    float*          qkb  = (float*)(ws + 176 * MB);
    float*          ss   = qkb + 512;     // 1024 f32
    float*          sums = qkb + 1536;    // 1024 f32 (BN accumulators)
    unsigned short* Wqk = W;
    unsigned short* Wvb = W + 512L * 768;
    unsigned short* Woa = W + 768L * 768;
    unsigned short* Wob = W + 1024L * 768;

    const dim3 blk(256);
    const long sIT = 1026L * 256, sQK = 1024L * 512, sV = 256L * 1024;

    prep<<<5478, blk, 0, stream>>>(image, clinical,
                                   a_qw, a_qb, a_kw, a_kb, a_vw, a_vb, a_ow,
                                   b_qw, b_qb, b_kw, b_kb, b_vw, b_vb, b_ow,
                                   imgT, ctxT, kTa, va, qTb, W, qkb, sums);
    // Dispatch 2 (merged): QK[l][co2] (512 blocks) + vb[co][l] (256 blocks), K=768
    {
        GOp opQ = {imgT, Wqk, QK, sIT, 0, sQK, 256, 768, 512, 4, 8, 16, nullptr, qkb, nullptr, 0};
        GOp opV = {Wvb, imgT, vb, 0, sIT, sV, 768, 256, 1024, 8, 2, 16, b_vb, nullptr, nullptr, 0};
        gemm_nt<<<768, blk, 0, stream>>>(opQ, opV, 512, 768, 1.f);
    }
    // Dispatch 3: fused attention (scores+softmax+ctx), both branches
    flash_attn<<<512, blk, 0, stream>>>(QK, qTb, kTa, va, vb, ctxT);
    // Dispatch 4: o-conv both branches -> Y bf16 + fused BN partial stats
    {
        GOp opA = {Woa, ctxT, Y, 0, sIT, sV, 768, 256, 1024, 8, 2, 16, a_ob, nullptr, sums, 0};
        GOp opB = {Wob, ctxT + 16 * sIT, Y + 16 * sV, 0, sIT, sV, 768, 256, 1024, 8, 2, 16, b_ob, nullptr, sums, 256};
        gemm_nt<<<512, blk, 0, stream>>>(opA, opB, 256, 768, 1.f);
    }
    // BN finalize + apply
    bn_finalize<<<2, blk, 0, stream>>>(sums, a_g, a_be, b_g, b_be, ss);
    bn_apply<<<8192, blk, 0, stream>>>(Y, image, ss, out);
}

// Round 4
// 308.551 us; speedup vs baseline: 1.2305x; 1.2305x over previous
//
#include <hip/hip_runtime.h>

// CrossSymmetricModal: two cross-attention branches. B=16, C=256, L=1024.
// Convs are NT-GEMMs over padded transposed activations with tap-major K.
// R9: flash attention (S never hits HBM). R10: XCD-swizzled grids, bf16 Y +
// BN stats fused into o-conv epilogue.
// R14: flash_attn = exact R0 structure but 32-row Q strips (mt loops 4->2),
// grid 1024 = 32 strips x 32 z.  LDS 53248->26624 B, VGPR ~124->~100 =>
// 4+ blocks/CU co-resident (was 2) to hide the per-tile dependent chain
// (QK -> softmax -> barrier -> PV) that left 90% stall at 2 waves/SIMD.
// R11/R12/R13 lessons: do NOT restructure wave roles (VGPR/conflict blowup),
// do NOT register-prefetch K wholesale (spills), keep per-wave layout.
// Output [16][512][1024] fp32.

typedef short bf16x8 __attribute__((ext_vector_type(8)));
typedef float f32x4 __attribute__((ext_vector_type(4)));

__device__ __forceinline__ unsigned short f2bf(float f) {
    union { float f; unsigned u; } v; v.f = f;
    unsigned r = v.u + 0x7fffu + ((v.u >> 16) & 1u);   // RNE
    return (unsigned short)(r >> 16);
}
__device__ __forceinline__ float bf2f(unsigned short h) {
    union { unsigned u; float f; } v; v.u = ((unsigned)h) << 16;
    return v.f;
}

// async global->LDS, 16B per lane; HW writes lane i at lds_base + i*16 (m97/m104)
__device__ __forceinline__ void glds16(const void* g, void* l) {
    __builtin_amdgcn_global_load_lds(
        (const __attribute__((address_space(1))) unsigned int*)g,
        (__attribute__((address_space(3))) unsigned int*)l, 16, 0, 0);
}

// ---------------------------------------------------------------------------
// NT GEMM: 2-op batched, compact 1-D grid, double-buffered glds staging,
// LDS-transpose epilogue with coalesced 16B stores.
// ---------------------------------------------------------------------------
#define TM 128
#define TN 128
#define BK 32

struct GOp {
    const unsigned short* A; const unsigned short* B; void* C;
    long sA, sB, sC;
    int lda, ldb, ldc, nxt, nyt, nz;
    const float* bias_row; const float* bias_col;
    float* stats; int stat_base;      // stats!=null: atomicAdd sum/sumsq per row
};

__global__ __launch_bounds__(256)
void gemm_nt(GOp op0, GOp op1, int n0, int K, float alpha)
{
    __shared__ __attribute__((aligned(16))) char sh[34816];
    unsigned short* shs = (unsigned short*)sh;
    int id = blockIdx.x;
    const bool brn = (id >= n0);
    const GOp op = brn ? op1 : op0;
    if (brn) id -= n0;
    const int bz = id % op.nz;          // XCD swizzle
    const int rem = id / op.nz;
    const int by = rem / op.nxt;
    const int bx = rem - by * op.nxt;

    const unsigned short* Ab = op.A + op.sA * bz;
    const unsigned short* Bb = op.B + op.sB * bz;
    const int lda = op.lda, ldb = op.ldb;
    const int i0 = by * TM;
    const int j0 = bx * TN;
    const int t = threadIdx.x;
    const int lane = t & 63;
    const int wave = t >> 6;
    const int wm = wave & 1, wn = wave >> 1;

    const int srow = wave * 16 + (lane >> 2);
    const int sc8 = (lane & 3) * 8;
    const unsigned short* gA0 = Ab + (long)(i0 + srow) * lda + sc8;
    const unsigned short* gA1 = gA0 + (long)64 * lda;
    const unsigned short* gB0 = Bb + (long)(j0 + srow) * ldb + sc8;
    const unsigned short* gB1 = gB0 + (long)64 * ldb;
    const int d0 = wave * 512;
    const int d1 = 2048 + wave * 512;

    f32x4 acc[4][4];
#pragma unroll
    for (int a_ = 0; a_ < 4; ++a_)
#pragma unroll
        for (int b_ = 0; b_ < 4; ++b_)
            acc[a_][b_] = (f32x4){0.f, 0.f, 0.f, 0.f};

    const int frow = lane & 15;
    const int fk = (lane >> 4) * 8;

    glds16(gA0, shs + d0);
    glds16(gA1, shs + d1);
    glds16(gB0, shs + 8192 + d0);
    glds16(gB1, shs + 8192 + d1);

    int cur = 0;
    for (int k0 = 0; k0 < K; k0 += BK) {
        __syncthreads();
        const int kn = k0 + BK;
        if (kn < K) {
            const int nb = cur ^ 1;
            glds16(gA0 + kn, shs + nb * 4096 + d0);
            glds16(gA1 + kn, shs + nb * 4096 + d1);
            glds16(gB0 + kn, shs + 8192 + nb * 4096 + d0);
            glds16(gB1 + kn, shs + 8192 + nb * 4096 + d1);
        }
        const unsigned short* la = shs + cur * 4096;
        const unsigned short* lb = shs + 8192 + cur * 4096;
        bf16x8 af[4], bfr[4];
#pragma unroll
        for (int mt = 0; mt < 4; ++mt)
            af[mt] = *(const bf16x8*)(&la[(wm * 64 + mt * 16 + frow) * BK + fk]);
#pragma unroll
        for (int nt = 0; nt < 4; ++nt)
            bfr[nt] = *(const bf16x8*)(&lb[(wn * 64 + nt * 16 + frow) * BK + fk]);
#pragma unroll
        for (int mt = 0; mt < 4; ++mt)
#pragma unroll
            for (int nt = 0; nt < 4; ++nt)
                acc[mt][nt] = __builtin_amdgcn_mfma_f32_16x16x32_bf16(af[mt], bfr[nt], acc[mt][nt], 0, 0, 0);
        cur ^= 1;
    }

    const int lr = (lane >> 4) * 4;   // C/D: row=(lane>>4)*4+reg, col=lane&15 (m89/m91)
    const int lc = lane & 15;
    __syncthreads();

    unsigned short* tile = shs;       // [128][136]
#pragma unroll
    for (int mt = 0; mt < 4; ++mt) {
#pragma unroll
        for (int nt = 0; nt < 4; ++nt) {
            const int col = wn * 64 + nt * 16 + lc;
            const float bc = op.bias_col ? op.bias_col[j0 + col] : 0.f;
#pragma unroll
            for (int r = 0; r < 4; ++r) {
                const int row = wm * 64 + mt * 16 + lr + r;
                const float brv = op.bias_row ? op.bias_row[i0 + row] : 0.f;
                tile[row * 136 + col] = f2bf(acc[mt][nt][r] * alpha + brv + bc);
            }
        }
    }
    __syncthreads();
    unsigned short* Cb = (unsigned short*)op.C + op.sC * bz;
#pragma unroll
    for (int p = 0; p < 8; ++p) {
        const int cid = p * 256 + t;
        const int row = cid >> 4;
        const int c8 = (cid & 15) * 8;
        const uint4 v = *(const uint4*)(tile + row * 136 + c8);
        *(uint4*)(Cb + (long)(i0 + row) * op.ldc + j0 + c8) = v;
    }
    if (op.stats) {
        // per-channel (row) partial sums of the bf16 tile; 2 threads/row
        const int row = t >> 1, half = t & 1;
        float s = 0.f, s2 = 0.f;
#pragma unroll
        for (int c = 0; c < 64; c += 8) {
            const bf16x8 v = *(const bf16x8*)(tile + row * 136 + half * 64 + c);
#pragma unroll
            for (int e = 0; e < 8; ++e) {
                const float f = bf2f((unsigned short)v[e]);
                s += f; s2 += f * f;
            }
        }
        s += __shfl_xor(s, 1);
        s2 += __shfl_xor(s2, 1);
        if (half == 0) {
            const int ch = op.stat_base + i0 + row;
            atomicAdd(&op.stats[ch], s);
            atomicAdd(&op.stats[512 + ch], s2);
        }
    }
}

// ---------------------------------------------------------------------------
// Fused flash attention, R0 structure at 32-row strips (R14).
// 256 threads / 4 waves.  Per 128-key tile: wave w owns keys [w*32,+32) in
// QK and channels [w*64,+64) in PV.  Grid 1024 = 32 strips x 32 z (z
// fastest => same-z strips on one XCD; K/V served from its 4MB L2).
// No max-subtraction (S/16 sigma~1.9, max~10 => exp<=4e4, f32-safe).
// ---------------------------------------------------------------------------
__global__ __launch_bounds__(256)
void flash_attn(const unsigned short* __restrict__ QK,
                const unsigned short* __restrict__ qTb,
                const unsigned short* __restrict__ kTa,
                const unsigned short* __restrict__ va,
                const unsigned short* __restrict__ vb,
                unsigned short* __restrict__ ctxT)
{
    __shared__ __attribute__((aligned(16))) char sh[26624];
    unsigned short* Qs = (unsigned short*)sh;            // [32][264]
    unsigned short* Ps = (unsigned short*)(sh + 16896);  // [32][136]
    float* lts = (float*)(sh + 25600);                   // [4][64]

    const long sQK = 1024L * 512, sQT = 1024L * 256, sV = 256L * 1024;
    const int bid = blockIdx.x;            // 1024 = 32 strips x 32 z (z fastest!)
    const int z = bid & 31;
    const int l0 = (bid >> 5) * 32;
    const bool bb = (z >= 16);
    const int zz = bb ? z - 16 : z;
    const unsigned short* Qg = bb ? (qTb + (long)zz * sQT) : (QK + (long)zz * sQK);
    const int ldq = bb ? 256 : 512;
    const unsigned short* Kg = bb ? (QK + (long)zz * sQK + 256) : (kTa + (long)zz * sQT);
    const int ldk = bb ? 512 : 256;
    const unsigned short* Vg = (bb ? vb : va) + (long)zz * sV;       // [c][m] ld 1024
    unsigned short* Og = ctxT + ((long)z * 1026 + 1 + l0) * 256;     // [32][256]
    const unsigned short* Qb = Qg + (long)l0 * ldq;

    const int t = threadIdx.x;
    const int lane = t & 63, w = t >> 6;
    const int g = lane >> 4, li = lane & 15;

#pragma unroll
    for (int p = 0; p < 4; ++p) {
        const int cid = p * 256 + t, row = cid >> 5, c8 = (cid & 31) * 8;
        const uint4 v = *(const uint4*)(Qb + (long)row * ldq + c8);
        *(uint4*)(Qs + row * 264 + c8) = v;
    }
    __syncthreads();

    f32x4 acc_o[2][4];
    f32x4 l_run[2];
#pragma unroll
    for (int mt = 0; mt < 2; ++mt) {
        l_run[mt] = (f32x4){0.f, 0.f, 0.f, 0.f};
#pragma unroll
        for (int nt = 0; nt < 4; ++nt)
            acc_o[mt][nt] = (f32x4){0.f, 0.f, 0.f, 0.f};
    }

    for (int m0 = 0; m0 < 1024; m0 += 128) {
        f32x4 acc_s[2][2];
#pragma unroll
        for (int mt = 0; mt < 2; ++mt) {
            acc_s[mt][0] = (f32x4){0.f, 0.f, 0.f, 0.f};
            acc_s[mt][1] = (f32x4){0.f, 0.f, 0.f, 0.f};
        }
        const unsigned short* Kt = Kg + (long)(m0 + w * 32) * ldk;
#pragma unroll
        for (int kt = 0; kt < 8; ++kt) {
            const bf16x8 bk0 = *(const bf16x8*)(Kt + (long)li * ldk + kt * 32 + g * 8);
            const bf16x8 bk1 = *(const bf16x8*)(Kt + (long)(16 + li) * ldk + kt * 32 + g * 8);
#pragma unroll
            for (int mt = 0; mt < 2; ++mt) {
                const bf16x8 aq = *(const bf16x8*)(Qs + (mt * 16 + li) * 264 + kt * 32 + g * 8);
                acc_s[mt][0] = __builtin_amdgcn_mfma_f32_16x16x32_bf16(aq, bk0, acc_s[mt][0], 0, 0, 0);
                acc_s[mt][1] = __builtin_amdgcn_mfma_f32_16x16x32_bf16(aq, bk1, acc_s[mt][1], 0, 0, 0);
            }
        }
        f32x4 rs[2];
#pragma unroll
        for (int mt = 0; mt < 2; ++mt) {
            rs[mt] = (f32x4){0.f, 0.f, 0.f, 0.f};
#pragma unroll
            for (int nt = 0; nt < 2; ++nt)
#pragma unroll
                for (int r = 0; r < 4; ++r) {
                    const float pv = __expf(acc_s[mt][nt][r] * 0.0625f);
                    acc_s[mt][nt][r] = pv;
                    rs[mt][r] += pv;
                }
        }
#pragma unroll
        for (int mask = 1; mask <= 8; mask <<= 1)
#pragma unroll
            for (int mt = 0; mt < 2; ++mt)
#pragma unroll
                for (int r = 0; r < 4; ++r)
                    rs[mt][r] += __shfl_xor(rs[mt][r], mask);
#pragma unroll
        for (int mt = 0; mt < 2; ++mt)
#pragma unroll
            for (int nt = 0; nt < 2; ++nt)
#pragma unroll
                for (int r = 0; r < 4; ++r)
                    Ps[(mt * 16 + g * 4 + r) * 136 + w * 32 + nt * 16 + li] =
                        f2bf(acc_s[mt][nt][r]);
        if (li == 0)
#pragma unroll
            for (int mt = 0; mt < 2; ++mt)
                *(f32x4*)(lts + w * 64 + mt * 16 + g * 4) = rs[mt];
        __syncthreads();
#pragma unroll
        for (int mt = 0; mt < 2; ++mt) {
            const int off = mt * 16 + g * 4;
            const f32x4 s0 = *(const f32x4*)(lts + off);
            const f32x4 s1 = *(const f32x4*)(lts + 64 + off);
            const f32x4 s2 = *(const f32x4*)(lts + 128 + off);
            const f32x4 s3 = *(const f32x4*)(lts + 192 + off);
            l_run[mt] += s0 + s1 + s2 + s3;
        }
#pragma unroll
        for (int kt2 = 0; kt2 < 4; ++kt2) {
            bf16x8 bv[4];
#pragma unroll
            for (int nt2 = 0; nt2 < 4; ++nt2)
                bv[nt2] = *(const bf16x8*)(Vg + (long)(w * 64 + nt2 * 16 + li) * 1024
                                           + m0 + kt2 * 32 + g * 8);
#pragma unroll
            for (int mt = 0; mt < 2; ++mt) {
                const bf16x8 ap = *(const bf16x8*)(Ps + (mt * 16 + li) * 136 + kt2 * 32 + g * 8);
#pragma unroll
                for (int nt2 = 0; nt2 < 4; ++nt2)
                    acc_o[mt][nt2] = __builtin_amdgcn_mfma_f32_16x16x32_bf16(ap, bv[nt2], acc_o[mt][nt2], 0, 0, 0);
            }
        }
        __syncthreads();
    }

    f32x4 inv[2];
#pragma unroll
    for (int mt = 0; mt < 2; ++mt)
#pragma unroll
        for (int r = 0; r < 4; ++r)
            inv[mt][r] = 1.f / l_run[mt][r];
#pragma unroll
    for (int mt = 0; mt < 2; ++mt)
#pragma unroll
        for (int nt2 = 0; nt2 < 4; ++nt2)
#pragma unroll
            for (int r = 0; r < 4; ++r)
                Qs[(mt * 16 + g * 4 + r) * 264 + w * 64 + nt2 * 16 + li] =
                    f2bf(acc_o[mt][nt2][r] * inv[mt][r]);
    __syncthreads();
#pragma unroll
    for (int p = 0; p < 4; ++p) {
        const int cid = p * 256 + t, row = cid >> 5, c8 = (cid & 31) * 8;
        *(uint4*)(Og + (long)row * 256 + c8) = *(const uint4*)(Qs + row * 264 + c8);
    }
}

// ---------------------------------------------------------------------------
// Fused prep; tail now also zeroes the BN stats accumulators (grid 5478).
// ---------------------------------------------------------------------------
__global__ __launch_bounds__(256)
void prep(const float* __restrict__ image, const float* __restrict__ cli,
          const float* __restrict__ a_qw, const float* __restrict__ a_qb,
          const float* __restrict__ a_kw, const float* __restrict__ a_kb,
          const float* __restrict__ a_vw, const float* __restrict__ a_vb,
          const float* __restrict__ a_ow,
          const float* __restrict__ b_qw, const float* __restrict__ b_qb,
          const float* __restrict__ b_kw, const float* __restrict__ b_kb,
          const float* __restrict__ b_vw, const float* __restrict__ b_vb,
          const float* __restrict__ b_ow,
          unsigned short* __restrict__ imgT, unsigned short* __restrict__ ctxT,
          unsigned short* __restrict__ kTa, unsigned short* __restrict__ va,
          unsigned short* __restrict__ qTb,
          unsigned short* __restrict__ W, float* __restrict__ qkb,
          float* __restrict__ sums)
{
    __shared__ char smem[64 * 65 * 4];
    const int b = blockIdx.x;
    const int t = threadIdx.x;
    if (b < 1024) {
        float* tile = (float*)smem;                      // [64][65]
        const int bt = b >> 6, rem = b & 63;
        const int l0 = (rem & 15) * 64, c0 = (rem >> 4) * 64;
        const float* xb = image + ((long)bt * 256 + c0) * 1024 + l0;
        for (int idx = t; idx < 4096; idx += 256) {
            const int cc = idx >> 6, ll = idx & 63;
            tile[cc * 65 + ll] = xb[(long)cc * 1024 + ll];
        }
        __syncthreads();
        unsigned short* op = imgT + ((long)bt * 1026 + l0 + 1) * 256 + c0;
        for (int idx = t; idx < 4096; idx += 256) {
            const int ll = idx >> 6, cc = idx & 63;
            op[(long)ll * 256 + cc] = f2bf(tile[cc * 65 + ll]);
        }
    } else if (b < 1536) {
        float* xs = (float*)smem;                        // [34]
        const int local = b - 1024;
        const int bz = local >> 5;
        const int l0 = (local & 31) * 32;
        if (t < 34) {
            const int l = l0 + t - 1;
            xs[t] = (l >= 0 && l < 1024) ? cli[(long)bz * 1024 + l] : 0.f;
        }
        __syncthreads();
        for (int i = t; i < 32 * 256; i += 256) {        // [l][c] outputs
            const int r = i >> 8, c = i & 255;
            const float x0 = xs[r], x1 = xs[r + 1], x2 = xs[r + 2];
            const float kv = a_kw[c * 3] * x0 + a_kw[c * 3 + 1] * x1 + a_kw[c * 3 + 2] * x2 + a_kb[c];
            const float qv = b_qw[c * 3] * x0 + b_qw[c * 3 + 1] * x1 + b_qw[c * 3 + 2] * x2 + b_qb[c];
            const long base = ((long)bz * 1024 + l0 + r) * 256 + c;
            kTa[base] = f2bf(kv);
            qTb[base] = f2bf(qv);
        }
        for (int i = t; i < 32 * 256; i += 256) {        // [c][l] output
            const int c = i >> 5, r = i & 31;
            const float x0 = xs[r], x1 = xs[r + 1], x2 = xs[r + 2];
            const float vv = a_vw[c * 3] * x0 + a_vw[c * 3 + 1] * x1 + a_vw[c * 3 + 2] * x2 + a_vb[c];
            va[((long)bz * 256 + c) * 1024 + l0 + r] = f2bf(vv);
        }
    } else if (b < 5376) {
        const int i = (b - 1536) * 256 + t;              // 0..983039
        const int row = i / 768;
        const int kk = i - row * 768;
        const int j = kk >> 8, ci = kk & 255;
        const float* src = (row < 256) ? a_qw : (row < 512) ? b_kw
                         : (row < 768) ? b_vw : (row < 1024) ? a_ow : b_ow;
        const int r = row & 255;
        W[i] = f2bf(src[r * 768 + ci * 3 + j]);
    } else {
        const int i = (b - 5376) * 256 + t;              // 0..26111
        if (i < 512) {
            qkb[i] = (i < 256) ? a_qb[i] : b_kb[i - 256];
        } else if (i < 512 + 8192) {
            const int p = i - 512;                       // imgT pad rows
            const int bi = p >> 9, rr = (p >> 8) & 1, c = p & 255;
            imgT[((long)bi * 1026 + (rr ? 1025 : 0)) * 256 + c] = 0;
        } else if (i < 512 + 8192 + 16384) {
            const int p = i - 512 - 8192;                // ctxT pad rows
            const int bz = p >> 9, rr = (p >> 8) & 1, c = p & 255;
            ctxT[((long)bz * 1026 + (rr ? 1025 : 0)) * 256 + c] = 0;
        } else if (i < 512 + 8192 + 16384 + 1024) {
            sums[i - 512 - 8192 - 16384] = 0.f;          // BN accumulators
        }
    }
}

// ---------------------------------------------------------------------------
// BN finalize: sums[ch], sums[512+ch] -> ss scale/shift.  2 blocks.
// ---------------------------------------------------------------------------
__global__ __launch_bounds__(256)
void bn_finalize(const float* __restrict__ sums,
                 const float* __restrict__ ag, const float* __restrict__ abeta,
                 const float* __restrict__ bg, const float* __restrict__ bbeta,
                 float* __restrict__ ss)
{
    const int ch = blockIdx.x * 256 + threadIdx.x;
    const int branch = ch >> 8, c = ch & 255;
    const float mean = sums[ch] * (1.f / 16384.f);
    const float var = sums[512 + ch] * (1.f / 16384.f) - mean * mean;  // biased
    const float inv = rsqrtf(var + 1e-5f);
    const float g = branch ? bg[c] : ag[c];
    const float be = branch ? bbeta[c] : abeta[c];
    const float sc = g * inv;
    ss[ch] = sc;
    ss[512 + ch] = be - mean * sc;
}

// out[b][ch][l] = y*scale + shift + image[b][ch&255][l]  (Y is bf16 now)
__global__ __launch_bounds__(256)
void bn_apply(const unsigned short* __restrict__ Y, const float* __restrict__ img,
              const float* __restrict__ ss, float* __restrict__ out)
{
    const long i4 = (long)blockIdx.x * 256 + threadIdx.x;
    const long e = i4 * 4;
    const int l = (int)(e & 1023);
    const int ch = (int)((e >> 10) & 511);
    const int b = (int)(e >> 19);
    const int branch = ch >> 8, c = ch & 255;
    const float sc = ss[ch], sh = ss[512 + ch];
    const long yoff = (((long)(branch * 16 + b)) * 256 + c) * 1024 + l;
    const long ioff = ((long)b * 256 + c) * 1024 + l;
    const ushort4 yv = *(const ushort4*)(Y + yoff);
    const float4 iv = *(const float4*)(img + ioff);
    float4 o;
    o.x = bf2f(yv.x) * sc + sh + iv.x;
    o.y = bf2f(yv.y) * sc + sh + iv.y;
    o.z = bf2f(yv.z) * sc + sh + iv.z;
    o.w = bf2f(yv.w) * sc + sh + iv.w;
    *(float4*)(out + e) = o;
}

// ---------------------------------------------------------------------------
extern "C" void kernel_launch(void* const* d_in, const int* in_sizes, int n_in,
                              void* d_out, int out_size, void* d_ws, size_t ws_size,
                              hipStream_t stream)
{
    const float* image    = (const float*)d_in[0];
    const float* clinical = (const float*)d_in[1];
    const float* a_qw = (const float*)d_in[2];  const float* a_qb = (const float*)d_in[3];
    const float* a_kw = (const float*)d_in[4];  const float* a_kb = (const float*)d_in[5];
    const float* a_vw = (const float*)d_in[6];  const float* a_vb = (const float*)d_in[7];
    const float* a_ow = (const float*)d_in[8];  const float* a_ob = (const float*)d_in[9];
    const float* a_g  = (const float*)d_in[10]; const float* a_be = (const float*)d_in[11];
    const float* b_qw = (const float*)d_in[12]; const float* b_qb = (const float*)d_in[13];
    const float* b_kw = (const float*)d_in[14]; const float* b_kb = (const float*)d_in[15];
    const float* b_vw = (const float*)d_in[16]; const float* b_vb = (const float*)d_in[17];
    const float* b_ow = (const float*)d_in[18]; const float* b_ob = (const float*)d_in[19];
    const float* b_g  = (const float*)d_in[20]; const float* b_be = (const float*)d_in[21];
    float* out = (float*)d_out;

    char* ws = (char*)d_ws;
    const long MB = 1048576L;
    unsigned short* imgT = (unsigned short*)(ws);              // [16][1026][256] bf16
    unsigned short* ctxT = (unsigned short*)(ws + 9 * MB);     // [32][1026][256] bf16
    unsigned short* kTa  = (unsigned short*)(ws + 27 * MB);    // [16][1024][256]
    unsigned short* qTb  = (unsigned short*)(ws + 36 * MB);
    unsigned short* va   = (unsigned short*)(ws + 46 * MB);    // [16][256][1024]
    unsigned short* vb   = (unsigned short*)(ws + 54 * MB);
    unsigned short* QK   = (unsigned short*)(ws + 62 * MB);    // [16][1024][512]
    unsigned short* Y    = (unsigned short*)(ws + 142 * MB);   // [32][256][1024] bf16
    unsigned short* W    = (unsigned short*)(ws + 174 * MB);   // [1280][768] bf16 tap-major
    float*          qkb  = (float*)(ws + 176 * MB);
    float*          ss   = qkb + 512;     // 1024 f32
    float*          sums = qkb + 1536;    // 1024 f32 (BN accumulators)
    unsigned short* Wqk = W;
    unsigned short* Wvb = W + 512L * 768;
    unsigned short* Woa = W + 768L * 768;
    unsigned short* Wob = W + 1024L * 768;

    const dim3 blk(256);
    const long sIT = 1026L * 256, sQK = 1024L * 512, sV = 256L * 1024;

    prep<<<5478, blk, 0, stream>>>(image, clinical,
                                   a_qw, a_qb, a_kw, a_kb, a_vw, a_vb, a_ow,
                                   b_qw, b_qb, b_kw, b_kb, b_vw, b_vb, b_ow,
                                   imgT, ctxT, kTa, va, qTb, W, qkb, sums);
    // Dispatch 2 (merged): QK[l][co2] (512 blocks) + vb[co][l] (256 blocks), K=768
    {
        GOp opQ = {imgT, Wqk, QK, sIT, 0, sQK, 256, 768, 512, 4, 8, 16, nullptr, qkb, nullptr, 0};
        GOp opV = {Wvb, imgT, vb, 0, sIT, sV, 768, 256, 1024, 8, 2, 16, b_vb, nullptr, nullptr, 0};
        gemm_nt<<<768, blk, 0, stream>>>(opQ, opV, 512, 768, 1.f);
    }
    // Dispatch 3: fused attention (scores+softmax+ctx), both branches
    flash_attn<<<1024, blk, 0, stream>>>(QK, qTb, kTa, va, vb, ctxT);
    // Dispatch 4: o-conv both branches -> Y bf16 + fused BN partial stats
    {
        GOp opA = {Woa, ctxT, Y, 0, sIT, sV, 768, 256, 1024, 8, 2, 16, a_ob, nullptr, sums, 0};
        GOp opB = {Wob, ctxT + 16 * sIT, Y + 16 * sV, 0, sIT, sV, 768, 256, 1024, 8, 2, 16, b_ob, nullptr, sums, 256};
        gemm_nt<<<512, blk, 0, stream>>>(opA, opB, 256, 768, 1.f);
    }
    // BN finalize + apply
    bn_finalize<<<2, blk, 0, stream>>>(sums, a_g, a_be, b_g, b_be, ss);
    bn_apply<<<8192, blk, 0, stream>>>(Y, image, ss, out);
}

// Round 5
// 276.021 us; speedup vs baseline: 1.3756x; 1.1179x over previous
//
#include <hip/hip_runtime.h>

// CrossSymmetricModal: two cross-attention branches. B=16, C=256, L=1024.
// R15: algebraic restructure. clinical is [B,1,L] so its convs are rank-4
// (3 taps + bias):
//  branch a: S_a = (A X + d 1^T)/16 with A=Q_a^T Wk, d=Q_a^T bk; softmax rows
//    sum to 1 => ctx_a = Wv t_hat + bv, t_hat[l] = sum_m P[l][m] X[:,m] / l[l].
//    Whole branch-a attention = streaming VALU kernel (no MFMA, no K/V reads).
//  branch b: S_b = (X^T Y + 1 c^T)/16 with Y=Wq^T K_b, c=bq^T K_b; P_b is
//    materialized bf16 and PV runs as a plain NT-GEMM in gemm_nt (glds16
//    double-buffered) with 1/l folded in as an epilogue row-scale.
// flash_attn is deleted (R0-R14: latency-structural 84-130us; all of QK^T
// and branch-a PV were algebraically removable).
// Output [16][512][1024] fp32.

typedef short bf16x8 __attribute__((ext_vector_type(8)));
typedef float f32x4 __attribute__((ext_vector_type(4)));

__device__ __forceinline__ unsigned short f2bf(float f) {
    union { float f; unsigned u; } v; v.f = f;
    unsigned r = v.u + 0x7fffu + ((v.u >> 16) & 1u);   // RNE
    return (unsigned short)(r >> 16);
}
__device__ __forceinline__ float bf2f(unsigned short h) {
    union { unsigned u; float f; } v; v.u = ((unsigned)h) << 16;
    return v.f;
}

// async global->LDS, 16B per lane; HW writes lane i at lds_base + i*16 (m97/m104)
__device__ __forceinline__ void glds16(const void* g, void* l) {
    __builtin_amdgcn_global_load_lds(
        (const __attribute__((address_space(1))) unsigned int*)g,
        (__attribute__((address_space(3))) unsigned int*)l, 16, 0, 0);
}

// ---------------------------------------------------------------------------
// NT GEMM: 2-op batched, compact 1-D grid, double-buffered glds staging,
// LDS-transpose epilogue with coalesced 16B stores.  Per-op K; optional
// epilogue row-scale (PV normalization) and BN partial-stats atomics.
// ---------------------------------------------------------------------------
#define TM 128
#define TN 128
#define BK 32

struct GOp {
    const unsigned short* A; const unsigned short* B; void* C;
    long sA, sB, sC;
    int lda, ldb, ldc, nxt, nyt, nz, K;
    const float* bias_row; const float* bias_col;
    const float* row_scale;           // scale C row (i0+row) by rs[bz*M + row]
    float* stats; int stat_base;      // stats!=null: atomicAdd sum/sumsq per row
};

__global__ __launch_bounds__(256)
void gemm_nt(GOp op0, GOp op1, int n0, float alpha)
{
    __shared__ __attribute__((aligned(16))) char sh[34816];
    unsigned short* shs = (unsigned short*)sh;
    int id = blockIdx.x;
    const bool brn = (id >= n0);
    const GOp op = brn ? op1 : op0;
    if (brn) id -= n0;
    const int bz = id % op.nz;          // XCD swizzle
    const int rem = id / op.nz;
    const int by = rem / op.nxt;
    const int bx = rem - by * op.nxt;

    const unsigned short* Ab = op.A + op.sA * bz;
    const unsigned short* Bb = op.B + op.sB * bz;
    const int lda = op.lda, ldb = op.ldb;
    const int i0 = by * TM;
    const int j0 = bx * TN;
    const int t = threadIdx.x;
    const int lane = t & 63;
    const int wave = t >> 6;
    const int wm = wave & 1, wn = wave >> 1;

    const int srow = wave * 16 + (lane >> 2);
    const int sc8 = (lane & 3) * 8;
    const unsigned short* gA0 = Ab + (long)(i0 + srow) * lda + sc8;
    const unsigned short* gA1 = gA0 + (long)64 * lda;
    const unsigned short* gB0 = Bb + (long)(j0 + srow) * ldb + sc8;
    const unsigned short* gB1 = gB0 + (long)64 * ldb;
    const int d0 = wave * 512;
    const int d1 = 2048 + wave * 512;

    f32x4 acc[4][4];
#pragma unroll
    for (int a_ = 0; a_ < 4; ++a_)
#pragma unroll
        for (int b_ = 0; b_ < 4; ++b_)
            acc[a_][b_] = (f32x4){0.f, 0.f, 0.f, 0.f};

    const int frow = lane & 15;
    const int fk = (lane >> 4) * 8;

    glds16(gA0, shs + d0);
    glds16(gA1, shs + d1);
    glds16(gB0, shs + 8192 + d0);
    glds16(gB1, shs + 8192 + d1);

    int cur = 0;
    for (int k0 = 0; k0 < op.K; k0 += BK) {
        __syncthreads();
        const int kn = k0 + BK;
        if (kn < op.K) {
            const int nb = cur ^ 1;
            glds16(gA0 + kn, shs + nb * 4096 + d0);
            glds16(gA1 + kn, shs + nb * 4096 + d1);
            glds16(gB0 + kn, shs + 8192 + nb * 4096 + d0);
            glds16(gB1 + kn, shs + 8192 + nb * 4096 + d1);
        }
        const unsigned short* la = shs + cur * 4096;
        const unsigned short* lb = shs + 8192 + cur * 4096;
        bf16x8 af[4], bfr[4];
#pragma unroll
        for (int mt = 0; mt < 4; ++mt)
            af[mt] = *(const bf16x8*)(&la[(wm * 64 + mt * 16 + frow) * BK + fk]);
#pragma unroll
        for (int nt = 0; nt < 4; ++nt)
            bfr[nt] = *(const bf16x8*)(&lb[(wn * 64 + nt * 16 + frow) * BK + fk]);
#pragma unroll
        for (int mt = 0; mt < 4; ++mt)
#pragma unroll
            for (int nt = 0; nt < 4; ++nt)
                acc[mt][nt] = __builtin_amdgcn_mfma_f32_16x16x32_bf16(af[mt], bfr[nt], acc[mt][nt], 0, 0, 0);
        cur ^= 1;
    }

    const int lr = (lane >> 4) * 4;   // C/D: row=(lane>>4)*4+reg, col=lane&15 (m89/m91)
    const int lc = lane & 15;
    __syncthreads();

    unsigned short* tile = shs;       // [128][136]
#pragma unroll
    for (int mt = 0; mt < 4; ++mt) {
#pragma unroll
        for (int nt = 0; nt < 4; ++nt) {
            const int col = wn * 64 + nt * 16 + lc;
            const float bc = op.bias_col ? op.bias_col[j0 + col] : 0.f;
#pragma unroll
            for (int r = 0; r < 4; ++r) {
                const int row = wm * 64 + mt * 16 + lr + r;
                const float brv = op.bias_row ? op.bias_row[i0 + row] : 0.f;
                const float rsv = op.row_scale
                    ? op.row_scale[(long)bz * (op.nyt * TM) + i0 + row] : 1.f;
                tile[row * 136 + col] = f2bf((acc[mt][nt][r] * alpha + brv + bc) * rsv);
            }
        }
    }
    __syncthreads();
    unsigned short* Cb = (unsigned short*)op.C + op.sC * bz;
#pragma unroll
    for (int p = 0; p < 8; ++p) {
        const int cid = p * 256 + t;
        const int row = cid >> 4;
        const int c8 = (cid & 15) * 8;
        const uint4 v = *(const uint4*)(tile + row * 136 + c8);
        *(uint4*)(Cb + (long)(i0 + row) * op.ldc + j0 + c8) = v;
    }
    if (op.stats) {
        // per-channel (row) partial sums of the bf16 tile; 2 threads/row
        const int row = t >> 1, half = t & 1;
        float s = 0.f, s2 = 0.f;
#pragma unroll
        for (int c = 0; c < 64; c += 8) {
            const bf16x8 v = *(const bf16x8*)(tile + row * 136 + half * 64 + c);
#pragma unroll
            for (int e = 0; e < 8; ++e) {
                const float f = bf2f((unsigned short)v[e]);
                s += f; s2 += f * f;
            }
        }
        s += __shfl_xor(s, 1);
        s2 += __shfl_xor(s2, 1);
        if (half == 0) {
            const int ch = op.stat_base + i0 + row;
            atomicAdd(&op.stats[ch], s);
            atomicAdd(&op.stats[512 + ch], s2);
        }
    }
}

// ---------------------------------------------------------------------------
// mats: per (z,l) row of QK buffer ([l][512]: cols 0-255 = Q_a, 256-511 = K_b)
//   A[l][j] = sum_c Q_a[c][l] a_kw[c][j],  d[l] = sum_c Q_a[c][l] a_kb[c]
//   Y[m][j] = sum_c K_b[c][m] b_qw[c][j],  cb[m] = sum_c K_b[c][m] b_qb[c]
// Outputs M4A[z][l] = (a0,a1,a2,d), M4Y[z][m] = (y0,y1,y2,cb).  Grid 64.
// ---------------------------------------------------------------------------
__global__ __launch_bounds__(256)
void mats(const unsigned short* __restrict__ QK,
          const float* __restrict__ a_kw, const float* __restrict__ a_kb,
          const float* __restrict__ b_qw, const float* __restrict__ b_qb,
          float* __restrict__ M4A, float* __restrict__ M4Y)
{
    const int z = blockIdx.x >> 2;
    const int l = ((blockIdx.x & 3) << 8) + threadIdx.x;
    const unsigned short* row = QK + ((long)z * 1024 + l) * 512;
    float a0 = 0.f, a1 = 0.f, a2 = 0.f, d = 0.f;
    float y0 = 0.f, y1 = 0.f, y2 = 0.f, cb = 0.f;
    for (int c8 = 0; c8 < 32; ++c8) {
        const bf16x8 q = *(const bf16x8*)(row + c8 * 8);
        const bf16x8 k = *(const bf16x8*)(row + 256 + c8 * 8);
#pragma unroll
        for (int e = 0; e < 8; ++e) {
            const int c = c8 * 8 + e;
            const float qv = bf2f((unsigned short)q[e]);
            const float kv = bf2f((unsigned short)k[e]);
            a0 += qv * a_kw[c * 3];     a1 += qv * a_kw[c * 3 + 1];
            a2 += qv * a_kw[c * 3 + 2]; d  += qv * a_kb[c];
            y0 += kv * b_qw[c * 3];     y1 += kv * b_qw[c * 3 + 1];
            y2 += kv * b_qw[c * 3 + 2]; cb += kv * b_qb[c];
        }
    }
    const long o = ((long)z * 1024 + l) * 4;
    *(float4*)(M4A + o) = make_float4(a0, a1, a2, d);
    *(float4*)(M4Y + o) = make_float4(y0, y1, y2, cb);
}

// ---------------------------------------------------------------------------
// attn_mid, grid 320:
//  b<64: branch a full attention. Per (z, 256-row l-chunk): stream m=0..1023
//    computing P=exp((A.X+d)/16) on the fly, accumulate t=(t0,t1,t2),l; then
//    ctx_a[c][l] = Wv[c].t_hat + bv[c] written coalesced to ctxT[z].
//  b>=64: branch b score gen. Per (z, 64-row l-chunk): P[l][m]=exp(S/16) in
//    bf16 to global (LDS-staged coalesced flush) + invl[z][l] = 1/rowsum.
// ---------------------------------------------------------------------------
__global__ __launch_bounds__(256)
void attn_mid(const float* __restrict__ cli,
              const float* __restrict__ M4A, const float* __restrict__ M4Y,
              const float* __restrict__ a_vw, const float* __restrict__ a_vb,
              unsigned short* __restrict__ P, float* __restrict__ invl,
              unsigned short* __restrict__ ctxT)
{
    __shared__ __attribute__((aligned(16))) char smem[38912];
    const int bid = blockIdx.x;
    const int t = threadIdx.x;
    if (bid < 64) {
        // ---------------- branch a ----------------
        const int z = bid >> 2;
        const int l0 = (bid & 3) << 8;
        float* xs = (float*)smem;                       // [1026]
        for (int i = t; i < 1026; i += 256) {
            const int l = i - 1;
            xs[i] = (l >= 0 && l < 1024) ? cli[(long)z * 1024 + l] : 0.f;
        }
        __syncthreads();
        const float4 A = *(const float4*)(M4A + ((long)z * 1024 + l0 + t) * 4);
        float t0a = 0.f, t1a = 0.f, t2a = 0.f, lsa = 0.f;
        float t0b = 0.f, t1b = 0.f, t2b = 0.f, lsb = 0.f;
#pragma unroll 8
        for (int m = 0; m < 1024; m += 2) {
            const float x0 = xs[m],     x1 = xs[m + 1], x2 = xs[m + 2];
            const float u0 = xs[m + 1], u1 = xs[m + 2], u2 = xs[m + 3];
            const float e0 = __expf((A.x * x0 + A.y * x1 + A.z * x2 + A.w) * 0.0625f);
            const float e1 = __expf((A.x * u0 + A.y * u1 + A.z * u2 + A.w) * 0.0625f);
            t0a += e0 * x0; t1a += e0 * x1; t2a += e0 * x2; lsa += e0;
            t0b += e1 * u0; t1b += e1 * u1; t2b += e1 * u2; lsb += e1;
        }
        const float inv = 1.f / (lsa + lsb);
        const float th0 = (t0a + t0b) * inv, th1 = (t1a + t1b) * inv,
                    th2 = (t2a + t2b) * inv;
        __syncthreads();
        float* tt = (float*)smem;                       // reuse: [256][4]
        *(float4*)(tt + t * 4) = make_float4(th0, th1, th2, 0.f);
        __syncthreads();
        const float wv0 = a_vw[t * 3], wv1 = a_vw[t * 3 + 1], wv2 = a_vw[t * 3 + 2];
        const float bv = a_vb[t];
        unsigned short* Ob = ctxT + ((long)z * 1026 + 1 + l0) * 256;
        for (int l = 0; l < 256; ++l) {
            const float4 th = *(const float4*)(tt + l * 4);
            Ob[(long)l * 256 + t] = f2bf(wv0 * th.x + wv1 * th.y + wv2 * th.z + bv);
        }
    } else {
        // ---------------- branch b score gen ----------------
        const int b2 = bid - 64;
        const int z = b2 >> 4;
        const int l0 = (b2 & 15) << 6;
        float* xs = (float*)smem;                       // [66]
        float* ys = (float*)(smem + 512);               // [256][4]
        unsigned short* Pt = (unsigned short*)(smem + 4608);   // [64][260]
        if (t < 66) {
            const int l = l0 + t - 1;
            xs[t] = (l >= 0 && l < 1024) ? cli[(long)z * 1024 + l] : 0.f;
        }
        const int li = t >> 2, mg = t & 3;
        unsigned short* Pg = P + (long)z * 1024 * 1024;
        float lsum = 0.f;
        float x0 = 0.f, x1 = 0.f, x2 = 0.f;
        for (int mc = 0; mc < 4; ++mc) {
            __syncthreads();
            *(float4*)(ys + t * 4) =
                *(const float4*)(M4Y + ((long)z * 1024 + mc * 256 + t) * 4);
            __syncthreads();
            if (mc == 0) { x0 = xs[li]; x1 = xs[li + 1]; x2 = xs[li + 2]; }
#pragma unroll
            for (int i8 = 0; i8 < 8; ++i8) {
                bf16x8 out;
#pragma unroll
                for (int e = 0; e < 8; ++e) {
                    const int m = mg * 64 + i8 * 8 + e;
                    const float4 y = *(const float4*)(ys + m * 4);
                    const float p =
                        __expf((x0 * y.x + x1 * y.y + x2 * y.z + y.w) * 0.0625f);
                    lsum += p;
                    out[e] = (short)f2bf(p);
                }
                *(bf16x8*)(Pt + li * 260 + mg * 64 + i8 * 8) = out;
            }
            __syncthreads();
#pragma unroll
            for (int p8 = 0; p8 < 8; ++p8) {
                const int cid = p8 * 256 + t;
                const int row = cid >> 5, c8 = (cid & 31) * 8;
                *(uint4*)(Pg + (long)(l0 + row) * 1024 + mc * 256 + c8) =
                    *(const uint4*)(Pt + row * 260 + c8);
            }
        }
        lsum += __shfl_xor(lsum, 1);
        lsum += __shfl_xor(lsum, 2);
        if (mg == 0)
            invl[(long)z * 1024 + l0 + li] = 1.f / lsum;
    }
}

// ---------------------------------------------------------------------------
// Fused prep (grid 4966): imgT transpose, W pack, qkb, pad zeroing, BN sums.
// ---------------------------------------------------------------------------
__global__ __launch_bounds__(256)
void prep(const float* __restrict__ image,
          const float* __restrict__ a_qw, const float* __restrict__ a_qb,
          const float* __restrict__ b_kw, const float* __restrict__ b_kb,
          const float* __restrict__ b_vw,
          const float* __restrict__ a_ow, const float* __restrict__ b_ow,
          unsigned short* __restrict__ imgT, unsigned short* __restrict__ ctxT,
          unsigned short* __restrict__ W, float* __restrict__ qkb,
          float* __restrict__ sums)
{
    __shared__ char smem[64 * 65 * 4];
    const int b = blockIdx.x;
    const int t = threadIdx.x;
    if (b < 1024) {
        float* tile = (float*)smem;                      // [64][65]
        const int bt = b >> 6, rem = b & 63;
        const int l0 = (rem & 15) * 64, c0 = (rem >> 4) * 64;
        const float* xb = image + ((long)bt * 256 + c0) * 1024 + l0;
        for (int idx = t; idx < 4096; idx += 256) {
            const int cc = idx >> 6, ll = idx & 63;
            tile[cc * 65 + ll] = xb[(long)cc * 1024 + ll];
        }
        __syncthreads();
        unsigned short* op = imgT + ((long)bt * 1026 + l0 + 1) * 256 + c0;
        for (int idx = t; idx < 4096; idx += 256) {
            const int ll = idx >> 6, cc = idx & 63;
            op[(long)ll * 256 + cc] = f2bf(tile[cc * 65 + ll]);
        }
    } else if (b < 4864) {
        const int i = (b - 1024) * 256 + t;              // 0..983039
        const int row = i / 768;
        const int kk = i - row * 768;
        const int j = kk >> 8, ci = kk & 255;
        const float* src = (row < 256) ? a_qw : (row < 512) ? b_kw
                         : (row < 768) ? b_vw : (row < 1024) ? a_ow : b_ow;
        const int r = row & 255;
        W[i] = f2bf(src[r * 768 + ci * 3 + j]);
    } else {
        const int i = (b - 4864) * 256 + t;              // 0..26111
        if (i < 512) {
            qkb[i] = (i < 256) ? a_qb[i] : b_kb[i - 256];
        } else if (i < 512 + 8192) {
            const int p = i - 512;                       // imgT pad rows
            const int bi = p >> 9, rr = (p >> 8) & 1, c = p & 255;
            imgT[((long)bi * 1026 + (rr ? 1025 : 0)) * 256 + c] = 0;
        } else if (i < 512 + 8192 + 16384) {
            const int p = i - 512 - 8192;                // ctxT pad rows
            const int bz = p >> 9, rr = (p >> 8) & 1, c = p & 255;
            ctxT[((long)bz * 1026 + (rr ? 1025 : 0)) * 256 + c] = 0;
        } else if (i < 512 + 8192 + 16384 + 1024) {
            sums[i - 512 - 8192 - 16384] = 0.f;          // BN accumulators
        }
    }
}

// ---------------------------------------------------------------------------
// BN finalize: sums[ch], sums[512+ch] -> ss scale/shift.  2 blocks.
// ---------------------------------------------------------------------------
__global__ __launch_bounds__(256)
void bn_finalize(const float* __restrict__ sums,
                 const float* __restrict__ ag, const float* __restrict__ abeta,
                 const float* __restrict__ bg, const float* __restrict__ bbeta,
                 float* __restrict__ ss)
{
    const int ch = blockIdx.x * 256 + threadIdx.x;
    const int branch = ch >> 8, c = ch & 255;
    const float mean = sums[ch] * (1.f / 16384.f);
    const float var = sums[512 + ch] * (1.f / 16384.f) - mean * mean;  // biased
    const float inv = rsqrtf(var + 1e-5f);
    const float g = branch ? bg[c] : ag[c];
    const float be = branch ? bbeta[c] : abeta[c];
    const float sc = g * inv;
    ss[ch] = sc;
    ss[512 + ch] = be - mean * sc;
}

// out[b][ch][l] = y*scale + shift + image[b][ch&255][l]  (Y is bf16)
__global__ __launch_bounds__(256)
void bn_apply(const unsigned short* __restrict__ Y, const float* __restrict__ img,
              const float* __restrict__ ss, float* __restrict__ out)
{
    const long i4 = (long)blockIdx.x * 256 + threadIdx.x;
    const long e = i4 * 4;
    const int l = (int)(e & 1023);
    const int ch = (int)((e >> 10) & 511);
    const int b = (int)(e >> 19);
    const int branch = ch >> 8, c = ch & 255;
    const float sc = ss[ch], sh = ss[512 + ch];
    const long yoff = (((long)(branch * 16 + b)) * 256 + c) * 1024 + l;
    const long ioff = ((long)b * 256 + c) * 1024 + l;
    const ushort4 yv = *(const ushort4*)(Y + yoff);
    const float4 iv = *(const float4*)(img + ioff);
    float4 o;
    o.x = bf2f(yv.x) * sc + sh + iv.x;
    o.y = bf2f(yv.y) * sc + sh + iv.y;
    o.z = bf2f(yv.z) * sc + sh + iv.z;
    o.w = bf2f(yv.w) * sc + sh + iv.w;
    *(float4*)(out + e) = o;
}

// ---------------------------------------------------------------------------
extern "C" void kernel_launch(void* const* d_in, const int* in_sizes, int n_in,
                              void* d_out, int out_size, void* d_ws, size_t ws_size,
                              hipStream_t stream)
{
    const float* image    = (const float*)d_in[0];
    const float* clinical = (const float*)d_in[1];
    const float* a_qw = (const float*)d_in[2];  const float* a_qb = (const float*)d_in[3];
    const float* a_kw = (const float*)d_in[4];  const float* a_kb = (const float*)d_in[5];
    const float* a_vw = (const float*)d_in[6];  const float* a_vb = (const float*)d_in[7];
    const float* a_ow = (const float*)d_in[8];  const float* a_ob = (const float*)d_in[9];
    const float* a_g  = (const float*)d_in[10]; const float* a_be = (const float*)d_in[11];
    const float* b_qw = (const float*)d_in[12]; const float* b_qb = (const float*)d_in[13];
    const float* b_kw = (const float*)d_in[14]; const float* b_kb = (const float*)d_in[15];
    const float* b_vw = (const float*)d_in[16]; const float* b_vb = (const float*)d_in[17];
    const float* b_ow = (const float*)d_in[18]; const float* b_ob = (const float*)d_in[19];
    const float* b_g  = (const float*)d_in[20]; const float* b_be = (const float*)d_in[21];
    float* out = (float*)d_out;

    char* ws = (char*)d_ws;
    const long MB = 1048576L;
    unsigned short* imgT = (unsigned short*)(ws);              // [16][1026][256] bf16
    unsigned short* ctxT = (unsigned short*)(ws + 9 * MB);     // [32][1026][256] bf16
    unsigned short* vb   = (unsigned short*)(ws + 54 * MB);    // [16][256][1024]
    unsigned short* QK   = (unsigned short*)(ws + 62 * MB);    // [16][1024][512]
    unsigned short* P    = (unsigned short*)(ws + 80 * MB);    // [16][1024][1024] bf16
    float*          M4A  = (float*)(ws + 114 * MB);            // [16][1024][4]
    float*          M4Y  = (float*)(ws + 115 * MB);            // [16][1024][4]
    float*          invl = (float*)(ws + 116 * MB);            // [16][1024]
    unsigned short* Y    = (unsigned short*)(ws + 142 * MB);   // [32][256][1024] bf16
    unsigned short* W    = (unsigned short*)(ws + 174 * MB);   // [1280][768] bf16 tap-major
    float*          qkb  = (float*)(ws + 176 * MB);
    float*          ss   = qkb + 512;     // 1024 f32
    float*          sums = qkb + 1536;    // 1024 f32 (BN accumulators)
    unsigned short* Wqk = W;
    unsigned short* Wvb = W + 512L * 768;
    unsigned short* Woa = W + 768L * 768;
    unsigned short* Wob = W + 1024L * 768;

    const dim3 blk(256);
    const long sIT = 1026L * 256, sQK = 1024L * 512, sV = 256L * 1024;
    const long sP = 1024L * 1024;

    prep<<<4966, blk, 0, stream>>>(image, a_qw, a_qb, b_kw, b_kb, b_vw,
                                   a_ow, b_ow, imgT, ctxT, W, qkb, sums);
    // Dispatch 2 (merged): QK[l][co2] (Q_a|K_b, 512 blocks) + vb[co][l] (256)
    {
        GOp opQ = {imgT, Wqk, QK, sIT, 0, sQK, 256, 768, 512, 4, 8, 16, 768,
                   nullptr, qkb, nullptr, nullptr, 0};
        GOp opV = {Wvb, imgT, vb, 0, sIT, sV, 768, 256, 1024, 8, 2, 16, 768,
                   b_vb, nullptr, nullptr, nullptr, 0};
        gemm_nt<<<768, blk, 0, stream>>>(opQ, opV, 512, 1.f);
    }
    // Dispatch 3: rank-4 mats A,d (branch a) and Y,c (branch b)
    mats<<<64, blk, 0, stream>>>(QK, a_kw, a_kb, b_qw, b_qb, M4A, M4Y);
    // Dispatch 4: branch-a streaming attention -> ctxT[0..16); branch-b P gen
    attn_mid<<<320, blk, 0, stream>>>(clinical, M4A, M4Y, a_vw, a_vb,
                                      P, invl, ctxT);
    // Dispatch 5: o-conv-a (-> Y bf16 + BN stats)  ||  PV_b (-> ctxT[16..32))
    {
        GOp opA = {Woa, ctxT, Y, 0, sIT, sV, 768, 256, 1024, 8, 2, 16, 768,
                   a_ob, nullptr, nullptr, sums, 0};
        GOp opPV = {P, vb, ctxT + 16 * sIT + 256, sP, sV, sIT, 1024, 1024, 256,
                    2, 8, 16, 1024, nullptr, nullptr, invl, nullptr, 0};
        gemm_nt<<<512, blk, 0, stream>>>(opA, opPV, 256, 1.f);
    }
    // Dispatch 6: o-conv-b -> Y bf16 + BN stats
    {
        GOp opB = {Wob, ctxT + 16 * sIT, Y + 16 * sV, 0, sIT, sV, 768, 256, 1024,
                   8, 2, 16, 768, b_ob, nullptr, nullptr, sums, 256};
        gemm_nt<<<256, blk, 0, stream>>>(opB, opB, 256, 1.f);
    }
    // BN finalize + apply
    bn_finalize<<<2, blk, 0, stream>>>(sums, a_g, a_be, b_g, b_be, ss);
    bn_apply<<<8192, blk, 0, stream>>>(Y, image, ss, out);
}

// Round 6
// 266.502 us; speedup vs baseline: 1.4247x; 1.0357x over previous
//
#include <hip/hip_runtime.h>

// CrossSymmetricModal: two cross-attention branches. B=16, C=256, L=1024.
// R15: algebraic restructure. clinical is [B,1,L] so its convs are rank-4
// (3 taps + bias):
//  branch a: S_a = (A X + d 1^T)/16 with A=Q_a^T Wk, d=Q_a^T bk; softmax rows
//    sum to 1 => ctx_a = Wv t_hat + bv, t_hat[l] = sum_m P[l][m] X[:,m] / l[l].
//  branch b: S_b = (X^T Y + 1 c^T)/16 with Y=Wq^T K_b, c=bq^T K_b; P_b is
//    materialized bf16 and PV runs as a plain NT-GEMM in gemm_nt with 1/l
//    folded in as an epilogue row-scale.
// R16: attn_mid re-gridded for occupancy (was 320 blocks = 1.25/CU, 7.4% occ,
// latency-exposed VALU).  Branch a: 256 blocks (64-row chunks, 4 thr/row +
// shfl reduce).  Branch b: 1024 blocks (16-row chunks), NO LDS -- y read as
// coalesced float4 from global (L1/L2-resident per z), P stored direct as
// bf16x8.  Grid 1280, heavy blocks first.
// Output [16][512][1024] fp32.

typedef short bf16x8 __attribute__((ext_vector_type(8)));
typedef float f32x4 __attribute__((ext_vector_type(4)));

__device__ __forceinline__ unsigned short f2bf(float f) {
    union { float f; unsigned u; } v; v.f = f;
    unsigned r = v.u + 0x7fffu + ((v.u >> 16) & 1u);   // RNE
    return (unsigned short)(r >> 16);
}
__device__ __forceinline__ float bf2f(unsigned short h) {
    union { unsigned u; float f; } v; v.u = ((unsigned)h) << 16;
    return v.f;
}

// async global->LDS, 16B per lane; HW writes lane i at lds_base + i*16 (m97/m104)
__device__ __forceinline__ void glds16(const void* g, void* l) {
    __builtin_amdgcn_global_load_lds(
        (const __attribute__((address_space(1))) unsigned int*)g,
        (__attribute__((address_space(3))) unsigned int*)l, 16, 0, 0);
}

// ---------------------------------------------------------------------------
// NT GEMM: 2-op batched, compact 1-D grid, double-buffered glds staging,
// LDS-transpose epilogue with coalesced 16B stores.  Per-op K; optional
// epilogue row-scale (PV normalization) and BN partial-stats atomics.
// ---------------------------------------------------------------------------
#define TM 128
#define TN 128
#define BK 32

struct GOp {
    const unsigned short* A; const unsigned short* B; void* C;
    long sA, sB, sC;
    int lda, ldb, ldc, nxt, nyt, nz, K;
    const float* bias_row; const float* bias_col;
    const float* row_scale;           // scale C row (i0+row) by rs[bz*M + row]
    float* stats; int stat_base;      // stats!=null: atomicAdd sum/sumsq per row
};

__global__ __launch_bounds__(256)
void gemm_nt(GOp op0, GOp op1, int n0, float alpha)
{
    __shared__ __attribute__((aligned(16))) char sh[34816];
    unsigned short* shs = (unsigned short*)sh;
    int id = blockIdx.x;
    const bool brn = (id >= n0);
    const GOp op = brn ? op1 : op0;
    if (brn) id -= n0;
    const int bz = id % op.nz;          // XCD swizzle
    const int rem = id / op.nz;
    const int by = rem / op.nxt;
    const int bx = rem - by * op.nxt;

    const unsigned short* Ab = op.A + op.sA * bz;
    const unsigned short* Bb = op.B + op.sB * bz;
    const int lda = op.lda, ldb = op.ldb;
    const int i0 = by * TM;
    const int j0 = bx * TN;
    const int t = threadIdx.x;
    const int lane = t & 63;
    const int wave = t >> 6;
    const int wm = wave & 1, wn = wave >> 1;

    const int srow = wave * 16 + (lane >> 2);
    const int sc8 = (lane & 3) * 8;
    const unsigned short* gA0 = Ab + (long)(i0 + srow) * lda + sc8;
    const unsigned short* gA1 = gA0 + (long)64 * lda;
    const unsigned short* gB0 = Bb + (long)(j0 + srow) * ldb + sc8;
    const unsigned short* gB1 = gB0 + (long)64 * ldb;
    const int d0 = wave * 512;
    const int d1 = 2048 + wave * 512;

    f32x4 acc[4][4];
#pragma unroll
    for (int a_ = 0; a_ < 4; ++a_)
#pragma unroll
        for (int b_ = 0; b_ < 4; ++b_)
            acc[a_][b_] = (f32x4){0.f, 0.f, 0.f, 0.f};

    const int frow = lane & 15;
    const int fk = (lane >> 4) * 8;

    glds16(gA0, shs + d0);
    glds16(gA1, shs + d1);
    glds16(gB0, shs + 8192 + d0);
    glds16(gB1, shs + 8192 + d1);

    int cur = 0;
    for (int k0 = 0; k0 < op.K; k0 += BK) {
        __syncthreads();
        const int kn = k0 + BK;
        if (kn < op.K) {
            const int nb = cur ^ 1;
            glds16(gA0 + kn, shs + nb * 4096 + d0);
            glds16(gA1 + kn, shs + nb * 4096 + d1);
            glds16(gB0 + kn, shs + 8192 + nb * 4096 + d0);
            glds16(gB1 + kn, shs + 8192 + nb * 4096 + d1);
        }
        const unsigned short* la = shs + cur * 4096;
        const unsigned short* lb = shs + 8192 + cur * 4096;
        bf16x8 af[4], bfr[4];
#pragma unroll
        for (int mt = 0; mt < 4; ++mt)
            af[mt] = *(const bf16x8*)(&la[(wm * 64 + mt * 16 + frow) * BK + fk]);
#pragma unroll
        for (int nt = 0; nt < 4; ++nt)
            bfr[nt] = *(const bf16x8*)(&lb[(wn * 64 + nt * 16 + frow) * BK + fk]);
#pragma unroll
        for (int mt = 0; mt < 4; ++mt)
#pragma unroll
            for (int nt = 0; nt < 4; ++nt)
                acc[mt][nt] = __builtin_amdgcn_mfma_f32_16x16x32_bf16(af[mt], bfr[nt], acc[mt][nt], 0, 0, 0);
        cur ^= 1;
    }

    const int lr = (lane >> 4) * 4;   // C/D: row=(lane>>4)*4+reg, col=lane&15 (m89/m91)
    const int lc = lane & 15;
    __syncthreads();

    unsigned short* tile = shs;       // [128][136]
#pragma unroll
    for (int mt = 0; mt < 4; ++mt) {
#pragma unroll
        for (int nt = 0; nt < 4; ++nt) {
            const int col = wn * 64 + nt * 16 + lc;
            const float bc = op.bias_col ? op.bias_col[j0 + col] : 0.f;
#pragma unroll
            for (int r = 0; r < 4; ++r) {
                const int row = wm * 64 + mt * 16 + lr + r;
                const float brv = op.bias_row ? op.bias_row[i0 + row] : 0.f;
                const float rsv = op.row_scale
                    ? op.row_scale[(long)bz * (op.nyt * TM) + i0 + row] : 1.f;
                tile[row * 136 + col] = f2bf((acc[mt][nt][r] * alpha + brv + bc) * rsv);
            }
        }
    }
    __syncthreads();
    unsigned short* Cb = (unsigned short*)op.C + op.sC * bz;
#pragma unroll
    for (int p = 0; p < 8; ++p) {
        const int cid = p * 256 + t;
        const int row = cid >> 4;
        const int c8 = (cid & 15) * 8;
        const uint4 v = *(const uint4*)(tile + row * 136 + c8);
        *(uint4*)(Cb + (long)(i0 + row) * op.ldc + j0 + c8) = v;
    }
    if (op.stats) {
        // per-channel (row) partial sums of the bf16 tile; 2 threads/row
        const int row = t >> 1, half = t & 1;
        float s = 0.f, s2 = 0.f;
#pragma unroll
        for (int c = 0; c < 64; c += 8) {
            const bf16x8 v = *(const bf16x8*)(tile + row * 136 + half * 64 + c);
#pragma unroll
            for (int e = 0; e < 8; ++e) {
                const float f = bf2f((unsigned short)v[e]);
                s += f; s2 += f * f;
            }
        }
        s += __shfl_xor(s, 1);
        s2 += __shfl_xor(s2, 1);
        if (half == 0) {
            const int ch = op.stat_base + i0 + row;
            atomicAdd(&op.stats[ch], s);
            atomicAdd(&op.stats[512 + ch], s2);
        }
    }
}

// ---------------------------------------------------------------------------
// mats: per (z,l) row of QK buffer ([l][512]: cols 0-255 = Q_a, 256-511 = K_b)
//   A[l][j] = sum_c Q_a[c][l] a_kw[c][j],  d[l] = sum_c Q_a[c][l] a_kb[c]
//   Y[m][j] = sum_c K_b[c][m] b_qw[c][j],  cb[m] = sum_c K_b[c][m] b_qb[c]
// Outputs M4A[z][l] = (a0,a1,a2,d), M4Y[z][m] = (y0,y1,y2,cb).  Grid 64.
// ---------------------------------------------------------------------------
__global__ __launch_bounds__(256)
void mats(const unsigned short* __restrict__ QK,
          const float* __restrict__ a_kw, const float* __restrict__ a_kb,
          const float* __restrict__ b_qw, const float* __restrict__ b_qb,
          float* __restrict__ M4A, float* __restrict__ M4Y)
{
    const int z = blockIdx.x >> 2;
    const int l = ((blockIdx.x & 3) << 8) + threadIdx.x;
    const unsigned short* row = QK + ((long)z * 1024 + l) * 512;
    float a0 = 0.f, a1 = 0.f, a2 = 0.f, d = 0.f;
    float y0 = 0.f, y1 = 0.f, y2 = 0.f, cb = 0.f;
    for (int c8 = 0; c8 < 32; ++c8) {
        const bf16x8 q = *(const bf16x8*)(row + c8 * 8);
        const bf16x8 k = *(const bf16x8*)(row + 256 + c8 * 8);
#pragma unroll
        for (int e = 0; e < 8; ++e) {
            const int c = c8 * 8 + e;
            const float qv = bf2f((unsigned short)q[e]);
            const float kv = bf2f((unsigned short)k[e]);
            a0 += qv * a_kw[c * 3];     a1 += qv * a_kw[c * 3 + 1];
            a2 += qv * a_kw[c * 3 + 2]; d  += qv * a_kb[c];
            y0 += kv * b_qw[c * 3];     y1 += kv * b_qw[c * 3 + 1];
            y2 += kv * b_qw[c * 3 + 2]; cb += kv * b_qb[c];
        }
    }
    const long o = ((long)z * 1024 + l) * 4;
    *(float4*)(M4A + o) = make_float4(a0, a1, a2, d);
    *(float4*)(M4Y + o) = make_float4(y0, y1, y2, cb);
}

// ---------------------------------------------------------------------------
// attn_mid, grid 1280 (R16):
//  bid<256: branch a. Block = (z = bid&15, 64-row chunk).  4 threads/row
//    stream 256 m each (xs in LDS), shfl_xor(1,2) reduce, t_hat to LDS;
//    epilogue: thread=channel writes ctx_a[c][l] for the 64 rows.
//  bid>=256: branch b. Block = (z, 16-row chunk), 16 threads/row.  NO LDS:
//    y as coalesced float4 from global (L1-resident), P direct bf16x8 to
//    global, rowsum via shfl_xor(1,2,4,8) over mg=t&15, invl by mg==0.
// ---------------------------------------------------------------------------
__global__ __launch_bounds__(256)
void attn_mid(const float* __restrict__ cli,
              const float* __restrict__ M4A, const float* __restrict__ M4Y,
              const float* __restrict__ a_vw, const float* __restrict__ a_vb,
              unsigned short* __restrict__ P, float* __restrict__ invl,
              unsigned short* __restrict__ ctxT)
{
    __shared__ __attribute__((aligned(16))) float smem[1032 + 256];  // xs | tt
    const int bid = blockIdx.x;
    const int t = threadIdx.x;
    if (bid < 256) {
        // ---------------- branch a ----------------
        const int z = bid & 15;
        const int l0 = (bid >> 4) << 6;
        float* xs = smem;                               // [1026]
        float* tt = smem + 1032;                        // [64][4]
        for (int i = t; i < 1026; i += 256) {
            const int l = i - 1;
            xs[i] = (l >= 0 && l < 1024) ? cli[(long)z * 1024 + l] : 0.f;
        }
        __syncthreads();
        const int r = t >> 2, q = t & 3;
        const float4 A = *(const float4*)(M4A + ((long)z * 1024 + l0 + r) * 4);
        float t0 = 0.f, t1 = 0.f, t2 = 0.f, ls = 0.f;
        const int m0 = q * 256;
#pragma unroll 4
        for (int m = m0; m < m0 + 256; ++m) {
            const float x0 = xs[m], x1 = xs[m + 1], x2 = xs[m + 2];
            const float e = __expf((A.x * x0 + A.y * x1 + A.z * x2 + A.w) * 0.0625f);
            t0 += e * x0; t1 += e * x1; t2 += e * x2; ls += e;
        }
        t0 += __shfl_xor(t0, 1); t0 += __shfl_xor(t0, 2);
        t1 += __shfl_xor(t1, 1); t1 += __shfl_xor(t1, 2);
        t2 += __shfl_xor(t2, 1); t2 += __shfl_xor(t2, 2);
        ls += __shfl_xor(ls, 1); ls += __shfl_xor(ls, 2);
        if (q == 0) *(float4*)(tt + r * 4) = make_float4(t0, t1, t2, ls);
        __syncthreads();
        const float wv0 = a_vw[t * 3], wv1 = a_vw[t * 3 + 1], wv2 = a_vw[t * 3 + 2];
        const float bv = a_vb[t];
        unsigned short* Ob = ctxT + ((long)z * 1026 + 1 + l0) * 256;
        for (int rr = 0; rr < 64; ++rr) {
            const float4 th = *(const float4*)(tt + rr * 4);
            const float inv = 1.f / th.w;
            Ob[(long)rr * 256 + t] = f2bf((wv0 * th.x + wv1 * th.y + wv2 * th.z) * inv + bv);
        }
    } else {
        // ---------------- branch b ----------------
        const int b2 = bid - 256;
        const int z = b2 & 15;
        const int l0 = (b2 >> 4) << 4;
        const int li = t >> 4, mg = t & 15;
        const int l = l0 + li;
        const float x0 = (l >= 1) ? cli[(long)z * 1024 + l - 1] : 0.f;
        const float x1 = cli[(long)z * 1024 + l];
        const float x2 = (l < 1023) ? cli[(long)z * 1024 + l + 1] : 0.f;
        const float4* Yz = (const float4*)(M4Y + (long)z * 4096);
        unsigned short* Pr = P + ((long)z * 1024 + l) * 1024;
        float lsum = 0.f;
#pragma unroll
        for (int jc = 0; jc < 4; ++jc)
#pragma unroll
            for (int i8 = 0; i8 < 2; ++i8) {
                const int mb = jc * 256 + mg * 16 + i8 * 8;
                bf16x8 out;
#pragma unroll
                for (int e = 0; e < 8; ++e) {
                    const float4 y = Yz[mb + e];
                    const float p = __expf((x0 * y.x + x1 * y.y + x2 * y.z + y.w) * 0.0625f);
                    lsum += p;
                    out[e] = (short)f2bf(p);
                }
                *(bf16x8*)(Pr + mb) = out;
            }
        lsum += __shfl_xor(lsum, 1); lsum += __shfl_xor(lsum, 2);
        lsum += __shfl_xor(lsum, 4); lsum += __shfl_xor(lsum, 8);
        if (mg == 0) invl[(long)z * 1024 + l] = 1.f / lsum;
    }
}

// ---------------------------------------------------------------------------
// Fused prep (grid 4966): imgT transpose, W pack, qkb, pad zeroing, BN sums.
// ---------------------------------------------------------------------------
__global__ __launch_bounds__(256)
void prep(const float* __restrict__ image,
          const float* __restrict__ a_qw, const float* __restrict__ a_qb,
          const float* __restrict__ b_kw, const float* __restrict__ b_kb,
          const float* __restrict__ b_vw,
          const float* __restrict__ a_ow, const float* __restrict__ b_ow,
          unsigned short* __restrict__ imgT, unsigned short* __restrict__ ctxT,
          unsigned short* __restrict__ W, float* __restrict__ qkb,
          float* __restrict__ sums)
{
    __shared__ char smem[64 * 65 * 4];
    const int b = blockIdx.x;
    const int t = threadIdx.x;
    if (b < 1024) {
        float* tile = (float*)smem;                      // [64][65]
        const int bt = b >> 6, rem = b & 63;
        const int l0 = (rem & 15) * 64, c0 = (rem >> 4) * 64;
        const float* xb = image + ((long)bt * 256 + c0) * 1024 + l0;
        for (int idx = t; idx < 4096; idx += 256) {
            const int cc = idx >> 6, ll = idx & 63;
            tile[cc * 65 + ll] = xb[(long)cc * 1024 + ll];
        }
        __syncthreads();
        unsigned short* op = imgT + ((long)bt * 1026 + l0 + 1) * 256 + c0;
        for (int idx = t; idx < 4096; idx += 256) {
            const int ll = idx >> 6, cc = idx & 63;
            op[(long)ll * 256 + cc] = f2bf(tile[cc * 65 + ll]);
        }
    } else if (b < 4864) {
        const int i = (b - 1024) * 256 + t;              // 0..983039
        const int row = i / 768;
        const int kk = i - row * 768;
        const int j = kk >> 8, ci = kk & 255;
        const float* src = (row < 256) ? a_qw : (row < 512) ? b_kw
                         : (row < 768) ? b_vw : (row < 1024) ? a_ow : b_ow;
        const int r = row & 255;
        W[i] = f2bf(src[r * 768 + ci * 3 + j]);
    } else {
        const int i = (b - 4864) * 256 + t;              // 0..26111
        if (i < 512) {
            qkb[i] = (i < 256) ? a_qb[i] : b_kb[i - 256];
        } else if (i < 512 + 8192) {
            const int p = i - 512;                       // imgT pad rows
            const int bi = p >> 9, rr = (p >> 8) & 1, c = p & 255;
            imgT[((long)bi * 1026 + (rr ? 1025 : 0)) * 256 + c] = 0;
        } else if (i < 512 + 8192 + 16384) {
            const int p = i - 512 - 8192;                // ctxT pad rows
            const int bz = p >> 9, rr = (p >> 8) & 1, c = p & 255;
            ctxT[((long)bz * 1026 + (rr ? 1025 : 0)) * 256 + c] = 0;
        } else if (i < 512 + 8192 + 16384 + 1024) {
            sums[i - 512 - 8192 - 16384] = 0.f;          // BN accumulators
        }
    }
}

// ---------------------------------------------------------------------------
// BN finalize: sums[ch], sums[512+ch] -> ss scale/shift.  2 blocks.
// ---------------------------------------------------------------------------
__global__ __launch_bounds__(256)
void bn_finalize(const float* __restrict__ sums,
                 const float* __restrict__ ag, const float* __restrict__ abeta,
                 const float* __restrict__ bg, const float* __restrict__ bbeta,
                 float* __restrict__ ss)
{
    const int ch = blockIdx.x * 256 + threadIdx.x;
    const int branch = ch >> 8, c = ch & 255;
    const float mean = sums[ch] * (1.f / 16384.f);
    const float var = sums[512 + ch] * (1.f / 16384.f) - mean * mean;  // biased
    const float inv = rsqrtf(var + 1e-5f);
    const float g = branch ? bg[c] : ag[c];
    const float be = branch ? bbeta[c] : abeta[c];
    const float sc = g * inv;
    ss[ch] = sc;
    ss[512 + ch] = be - mean * sc;
}

// out[b][ch][l] = y*scale + shift + image[b][ch&255][l]  (Y is bf16)
__global__ __launch_bounds__(256)
void bn_apply(const unsigned short* __restrict__ Y, const float* __restrict__ img,
              const float* __restrict__ ss, float* __restrict__ out)
{
    const long i4 = (long)blockIdx.x * 256 + threadIdx.x;
    const long e = i4 * 4;
    const int l = (int)(e & 1023);
    const int ch = (int)((e >> 10) & 511);
    const int b = (int)(e >> 19);
    const int branch = ch >> 8, c = ch & 255;
    const float sc = ss[ch], sh = ss[512 + ch];
    const long yoff = (((long)(branch * 16 + b)) * 256 + c) * 1024 + l;
    const long ioff = ((long)b * 256 + c) * 1024 + l;
    const ushort4 yv = *(const ushort4*)(Y + yoff);
    const float4 iv = *(const float4*)(img + ioff);
    float4 o;
    o.x = bf2f(yv.x) * sc + sh + iv.x;
    o.y = bf2f(yv.y) * sc + sh + iv.y;
    o.z = bf2f(yv.z) * sc + sh + iv.z;
    o.w = bf2f(yv.w) * sc + sh + iv.w;
    *(float4*)(out + e) = o;
}

// ---------------------------------------------------------------------------
extern "C" void kernel_launch(void* const* d_in, const int* in_sizes, int n_in,
                              void* d_out, int out_size, void* d_ws, size_t ws_size,
                              hipStream_t stream)
{
    const float* image    = (const float*)d_in[0];
    const float* clinical = (const float*)d_in[1];
    const float* a_qw = (const float*)d_in[2];  const float* a_qb = (const float*)d_in[3];
    const float* a_kw = (const float*)d_in[4];  const float* a_kb = (const float*)d_in[5];
    const float* a_vw = (const float*)d_in[6];  const float* a_vb = (const float*)d_in[7];
    const float* a_ow = (const float*)d_in[8];  const float* a_ob = (const float*)d_in[9];
    const float* a_g  = (const float*)d_in[10]; const float* a_be = (const float*)d_in[11];
    const float* b_qw = (const float*)d_in[12]; const float* b_qb = (const float*)d_in[13];
    const float* b_kw = (const float*)d_in[14]; const float* b_kb = (const float*)d_in[15];
    const float* b_vw = (const float*)d_in[16]; const float* b_vb = (const float*)d_in[17];
    const float* b_ow = (const float*)d_in[18]; const float* b_ob = (const float*)d_in[19];
    const float* b_g  = (const float*)d_in[20]; const float* b_be = (const float*)d_in[21];
    float* out = (float*)d_out;

    char* ws = (char*)d_ws;
    const long MB = 1048576L;
    unsigned short* imgT = (unsigned short*)(ws);              // [16][1026][256] bf16
    unsigned short* ctxT = (unsigned short*)(ws + 9 * MB);     // [32][1026][256] bf16
    unsigned short* vb   = (unsigned short*)(ws + 54 * MB);    // [16][256][1024]
    unsigned short* QK   = (unsigned short*)(ws + 62 * MB);    // [16][1024][512]
    unsigned short* P    = (unsigned short*)(ws + 80 * MB);    // [16][1024][1024] bf16
    float*          M4A  = (float*)(ws + 114 * MB);            // [16][1024][4]
    float*          M4Y  = (float*)(ws + 115 * MB);            // [16][1024][4]
    float*          invl = (float*)(ws + 116 * MB);            // [16][1024]
    unsigned short* Y    = (unsigned short*)(ws + 142 * MB);   // [32][256][1024] bf16
    unsigned short* W    = (unsigned short*)(ws + 174 * MB);   // [1280][768] bf16 tap-major
    float*          qkb  = (float*)(ws + 176 * MB);
    float*          ss   = qkb + 512;     // 1024 f32
    float*          sums = qkb + 1536;    // 1024 f32 (BN accumulators)
    unsigned short* Wqk = W;
    unsigned short* Wvb = W + 512L * 768;
    unsigned short* Woa = W + 768L * 768;
    unsigned short* Wob = W + 1024L * 768;

    const dim3 blk(256);
    const long sIT = 1026L * 256, sQK = 1024L * 512, sV = 256L * 1024;
    const long sP = 1024L * 1024;

    prep<<<4966, blk, 0, stream>>>(image, a_qw, a_qb, b_kw, b_kb, b_vw,
                                   a_ow, b_ow, imgT, ctxT, W, qkb, sums);
    // Dispatch 2 (merged): QK[l][co2] (Q_a|K_b, 512 blocks) + vb[co][l] (256)
    {
        GOp opQ = {imgT, Wqk, QK, sIT, 0, sQK, 256, 768, 512, 4, 8, 16, 768,
                   nullptr, qkb, nullptr, nullptr, 0};
        GOp opV = {Wvb, imgT, vb, 0, sIT, sV, 768, 256, 1024, 8, 2, 16, 768,
                   b_vb, nullptr, nullptr, nullptr, 0};
        gemm_nt<<<768, blk, 0, stream>>>(opQ, opV, 512, 1.f);
    }
    // Dispatch 3: rank-4 mats A,d (branch a) and Y,c (branch b)
    mats<<<64, blk, 0, stream>>>(QK, a_kw, a_kb, b_qw, b_qb, M4A, M4Y);
    // Dispatch 4: branch-a streaming attention -> ctxT[0..16); branch-b P gen
    attn_mid<<<1280, blk, 0, stream>>>(clinical, M4A, M4Y, a_vw, a_vb,
                                       P, invl, ctxT);
    // Dispatch 5: o-conv-a (-> Y bf16 + BN stats)  ||  PV_b (-> ctxT[16..32))
    {
        GOp opA = {Woa, ctxT, Y, 0, sIT, sV, 768, 256, 1024, 8, 2, 16, 768,
                   a_ob, nullptr, nullptr, sums, 0};
        GOp opPV = {P, vb, ctxT + 16 * sIT + 256, sP, sV, sIT, 1024, 1024, 256,
                    2, 8, 16, 1024, nullptr, nullptr, invl, nullptr, 0};
        gemm_nt<<<512, blk, 0, stream>>>(opA, opPV, 256, 1.f);
    }
    // Dispatch 6: o-conv-b -> Y bf16 + BN stats
    {
        GOp opB = {Wob, ctxT + 16 * sIT, Y + 16 * sV, 0, sIT, sV, 768, 256, 1024,
                   8, 2, 16, 768, b_ob, nullptr, nullptr, sums, 256};
        gemm_nt<<<256, blk, 0, stream>>>(opB, opB, 256, 1.f);
    }
    // BN finalize + apply
    bn_finalize<<<2, blk, 0, stream>>>(sums, a_g, a_be, b_g, b_be, ss);
    bn_apply<<<8192, blk, 0, stream>>>(Y, image, ss, out);
}